// Round 6
// baseline (613.025 us; speedup 1.0000x reference)
//
#include <hip/hip_runtime.h>
#include <stdint.h>

typedef unsigned short ushort_t;
typedef __attribute__((ext_vector_type(8))) __bf16 bf16x8;
typedef __attribute__((ext_vector_type(4))) float f32x4;

__device__ __forceinline__ float b2f(ushort_t u) {
    unsigned v = ((unsigned)u) << 16;
    float f;
    __builtin_memcpy(&f, &v, 4);
    return f;
}

__device__ __forceinline__ ushort_t f2b(float f) {
    unsigned u;
    __builtin_memcpy(&u, &f, 4);
    unsigned rounding = 0x7FFFu + ((u >> 16) & 1u);
    u += rounding;
    return (ushort_t)(u >> 16);
}

__device__ __forceinline__ void gl_lds16(const void* g, void* l) {
    __builtin_amdgcn_global_load_lds((const __attribute__((address_space(1))) void*)g,
                                     (__attribute__((address_space(3))) void*)l, 16, 0, 0);
}

// ---------------------------------------------------------------------------
// fp32 -> bf16 conversion (for weight matrices)
__global__ __launch_bounds__(256) void k_cvt(const float* __restrict__ src,
                                             ushort_t* __restrict__ dst, int n) {
    int i = blockIdx.x * 256 + threadIdx.x;
    if (i < n) dst[i] = f2b(src[i]);
}

// ---------------------------------------------------------------------------
// sdat[b][s] = (x, y, z, |p|^2) with |p|^2 = ((x*x + y*y) + z*z), strict fp32
// (torch square_distance norm order, no contraction)
__global__ __launch_bounds__(256) void k_sdat(const float* __restrict__ xyz2,
                                              float4* __restrict__ sdat) {
    int b = blockIdx.x;
    int s = blockIdx.y * 256 + threadIdx.x;
    const float* x2 = xyz2 + (size_t)b * 3 * 1024;
    float x = x2[s], y = x2[1024 + s], z = x2[2048 + s];
    float4 v;
    v.x = x; v.y = y; v.z = z;
    v.w = __fadd_rn(__fadd_rn(__fmul_rn(x, x), __fmul_rn(y, y)), __fmul_rn(z, z));
    sdat[(size_t)b * 1024 + s] = v;
}

// ---------------------------------------------------------------------------
// Transpose points2 [16][128][1024] (fp32) -> p2t [16][1024][128] (bf16)
__global__ __launch_bounds__(256) void k_p2t(const float* __restrict__ points2,
                                             ushort_t* __restrict__ p2t) {
    int b = blockIdx.x;
    int s = blockIdx.y * 256 + threadIdx.x;
    const float* src = points2 + (size_t)b * 128 * 1024 + s;
    ushort_t* dst = p2t + ((size_t)b * 1024 + s) * 128;
    for (int cp = 0; cp < 16; ++cp) {
        ushort_t tmp[8];
#pragma unroll
        for (int k = 0; k < 8; ++k) tmp[k] = f2b(src[(size_t)(cp * 8 + k) * 1024]);
        *(uint4*)(dst + cp * 8) = *(const uint4*)tmp;
    }
}

// ---------------------------------------------------------------------------
// 3-NN + build X [65536][512] bf16 (B^T layout for GEMM0)
// Distance: torch square_distance association, strict fp32:
//   dot = fma(z,pz, fma(y,py, x*px))       (BLAS K-ascending fma chain)
//   d   = ((-2*dot) + |q|^2) + |p|^2        (subtract-first association)
// Selection: ascending-s scan, strict <  (== stable sort, lowest index wins)
__global__ __launch_bounds__(256) void k_interp(const float* __restrict__ xyz1,
                                                const float4* __restrict__ sdat,
                                                const float* __restrict__ points1,
                                                const ushort_t* __restrict__ p2t,
                                                ushort_t* __restrict__ X) {
    int b = blockIdx.x;
    int n0 = blockIdx.y * 256;
    int t = threadIdx.x;

    __shared__ int sidx[256 * 3];
    __shared__ float sw[256 * 3];

    int n = n0 + t;
    float x = xyz1[((size_t)b * 3 + 0) * 4096 + n];
    float y = xyz1[((size_t)b * 3 + 1) * 4096 + n];
    float z = xyz1[((size_t)b * 3 + 2) * 4096 + n];
    float s1 = __fadd_rn(__fadd_rn(__fmul_rn(x, x), __fmul_rn(y, y)), __fmul_rn(z, z));

    const float4* sd = sdat + (size_t)b * 1024;

    float d0 = 1e30f, d1 = 1e30f, d2 = 1e30f;
    int i0 = 0, i1 = 0, i2 = 0;
    for (int s = 0; s < 1024; ++s) {
        float4 v = sd[s];
        float dot = fmaf(z, v.z, fmaf(y, v.y, __fmul_rn(x, v.x)));
        float d = __fadd_rn(__fadd_rn(__fmul_rn(-2.0f, dot), s1), v.w);
        if (d < d2) {
            if (d < d1) {
                if (d < d0) { d2 = d1; i2 = i1; d1 = d0; i1 = i0; d0 = d; i0 = s; }
                else        { d2 = d1; i2 = i1; d1 = d;  i1 = s; }
            } else          { d2 = d;  i2 = s; }
        }
    }
    // weights in fp32 (matches an fp32 np/torch reference; negative-d blowup
    // semantics preserved intentionally)
    float r0 = 1.0f / (d0 + 1e-8f), r1 = 1.0f / (d1 + 1e-8f), r2 = 1.0f / (d2 + 1e-8f);
    float rs = r0 + r1 + r2;
    sw[t * 3 + 0] = r0 / rs; sw[t * 3 + 1] = r1 / rs; sw[t * 3 + 2] = r2 / rs;
    sidx[t * 3 + 0] = i0; sidx[t * 3 + 1] = i1; sidx[t * 3 + 2] = i2;

    // points1 part: X[j][0:128] = bf16(points1[b][:, n])
    {
        const float* p1 = points1 + (size_t)b * 128 * 4096 + n;
        ushort_t* dst = X + (size_t)(b * 4096 + n) * 512;
        for (int cp = 0; cp < 16; ++cp) {
            ushort_t tmp[8];
#pragma unroll
            for (int k = 0; k < 8; ++k) tmp[k] = f2b(p1[(size_t)(cp * 8 + k) * 4096]);
            *(uint4*)(dst + cp * 8) = *(const uint4*)tmp;
        }
    }
    __syncthreads();

    // interp part: X[j][128 + r*128 + d] = bf16(w_r * p2t[b][idx_r][d])
    for (int qq = t; qq < 256 * 48; qq += 256) {
        int nl = qq / 48;
        int rem = qq - nl * 48;
        int r = rem >> 4;
        int piece = rem & 15;
        int si = sidx[nl * 3 + r];
        float wt = sw[nl * 3 + r];
        const ushort_t* src = p2t + ((size_t)b * 1024 + si) * 128 + piece * 8;
        uint4 raw = *(const uint4*)src;
        ushort_t* e = (ushort_t*)&raw;
        ushort_t outv[8];
#pragma unroll
        for (int k = 0; k < 8; ++k) outv[k] = f2b(wt * b2f(e[k]));
        ushort_t* dst = X + (size_t)(b * 4096 + n0 + nl) * 512 + 128 + r * 128 + piece * 8;
        *(uint4*)dst = *(const uint4*)outv;
    }
}

// ---------------------------------------------------------------------------
// GEMM: Y[j][o] = sum_k A[o][k]*Bt[j][k] + bias[o]; also per-o sum/sumsq atomics
__global__ __launch_bounds__(256) void k_gemm(const ushort_t* __restrict__ A,
                                              const ushort_t* __restrict__ Bt,
                                              const float* __restrict__ bias,
                                              ushort_t* __restrict__ Y,
                                              float* __restrict__ sum,
                                              float* __restrict__ ssq,
                                              int Mtot, int K) {
    __shared__ __align__(16) ushort_t As[128 * 32];
    __shared__ __align__(16) ushort_t Bs[128 * 32];

    int t = threadIdx.x;
    int m0 = blockIdx.x * 128;
    int j0 = blockIdx.y * 128;
    int wave = t >> 6, lane = t & 63;
    int wm = wave >> 1, wn = wave & 1;
    int l16 = lane & 15, quad = lane >> 4;

    f32x4 acc[4][4] = {};

    int nk = K >> 5;
    for (int kt = 0; kt < nk; ++kt) {
#pragma unroll
        for (int c = 0; c < 2; ++c) {
            int idx = c * 256 + t;
            int row = idx >> 2, kc = idx & 3;
            const ushort_t* srcA = A + (size_t)(m0 + row) * K + kt * 32 + kc * 8;
            const ushort_t* srcB = Bt + (size_t)(j0 + row) * K + kt * 32 + kc * 8;
            gl_lds16(srcA, As + idx * 8);
            gl_lds16(srcB, Bs + idx * 8);
        }
        __syncthreads();

        bf16x8 af[4], bfr[4];
#pragma unroll
        for (int mi = 0; mi < 4; ++mi)
            af[mi] = *(const bf16x8*)(As + (wm * 64 + mi * 16 + l16) * 32 + quad * 8);
#pragma unroll
        for (int ni = 0; ni < 4; ++ni)
            bfr[ni] = *(const bf16x8*)(Bs + (wn * 64 + ni * 16 + l16) * 32 + quad * 8);
#pragma unroll
        for (int mi = 0; mi < 4; ++mi)
#pragma unroll
            for (int ni = 0; ni < 4; ++ni)
                acc[mi][ni] = __builtin_amdgcn_mfma_f32_16x16x32_bf16(af[mi], bfr[ni], acc[mi][ni], 0, 0, 0);
        __syncthreads();
    }

#pragma unroll
    for (int mi = 0; mi < 4; ++mi) {
#pragma unroll
        for (int r = 0; r < 4; ++r) {
            int o = m0 + wm * 64 + mi * 16 + quad * 4 + r;
            float bv = bias[o];
            float s = 0.f, q = 0.f;
#pragma unroll
            for (int ni = 0; ni < 4; ++ni) {
                float v = acc[mi][ni][r] + bv;
                int j = j0 + wn * 64 + ni * 16 + l16;
                Y[(size_t)j * Mtot + o] = f2b(v);
                s += v;
                q += v * v;
            }
            s += __shfl_xor(s, 1); s += __shfl_xor(s, 2);
            s += __shfl_xor(s, 4); s += __shfl_xor(s, 8);
            q += __shfl_xor(q, 1); q += __shfl_xor(q, 2);
            q += __shfl_xor(q, 4); q += __shfl_xor(q, 8);
            if (l16 == 0) {
                atomicAdd(&sum[o], s);
                atomicAdd(&ssq[o], q);
            }
        }
    }
}

// ---------------------------------------------------------------------------
__global__ void k_bnfin(const float* __restrict__ sum, const float* __restrict__ ssq,
                        const float* __restrict__ gamma, const float* __restrict__ beta,
                        float* __restrict__ a, float* __restrict__ bb, int C, float inv_count) {
    int i = blockIdx.x * blockDim.x + threadIdx.x;
    if (i < C) {
        float mean = sum[i] * inv_count;
        float var = ssq[i] * inv_count - mean * mean;
        float sc = gamma[i] / sqrtf(var + 1e-5f);
        a[i] = sc;
        bb[i] = beta[i] - mean * sc;
    }
}

// ---------------------------------------------------------------------------
// In-place BN+ReLU on Y [cols][C] bf16 (C=256)
__global__ __launch_bounds__(256) void k_act(ushort_t* __restrict__ Y,
                                             const float* __restrict__ a,
                                             const float* __restrict__ bb,
                                             int total8) {
    __shared__ float sa[256], sb[256];
    for (int i = threadIdx.x; i < 256; i += 256) { sa[i] = a[i]; sb[i] = bb[i]; }
    __syncthreads();
    int idx = blockIdx.x * 256 + threadIdx.x;
    if (idx < total8) {
        ushort_t* p = Y + (size_t)idx * 8;
        int c0 = (idx * 8) & 255;
        uint4 raw = *(const uint4*)p;
        ushort_t* e = (ushort_t*)&raw;
#pragma unroll
        for (int k = 0; k < 8; ++k) {
            float v = b2f(e[k]);
            v = fmaxf(sa[c0 + k] * v + sb[c0 + k], 0.f);
            e[k] = f2b(v);
        }
        *(uint4*)p = raw;
    }
}

// ---------------------------------------------------------------------------
// Final BN+ReLU + transpose: Y1 [65536][128] bf16 -> out [16][128][4096] fp32
__global__ __launch_bounds__(256) void k_out(const ushort_t* __restrict__ Y1,
                                             const float* __restrict__ a,
                                             const float* __restrict__ bb,
                                             float* __restrict__ out) {
    __shared__ float sa[128], sb[128];
    int t = threadIdx.x;
    if (t < 128) { sa[t] = a[t]; sb[t] = bb[t]; }
    __syncthreads();
    int b = blockIdx.x;
    int n = blockIdx.y * 256 + t;
    const uint4* src = (const uint4*)(Y1 + (size_t)(b * 4096 + n) * 128);
    float* dst = out + (size_t)b * 128 * 4096 + n;
    uint4 raw[16];
#pragma unroll
    for (int p = 0; p < 16; ++p) raw[p] = src[p];
    const ushort_t* e = (const ushort_t*)raw;
#pragma unroll
    for (int c = 0; c < 128; ++c) {
        float v = b2f(e[c]);
        v = fmaxf(sa[c] * v + sb[c], 0.f);
        dst[(size_t)c * 4096] = v;
    }
}

// ---------------------------------------------------------------------------
extern "C" void kernel_launch(void* const* d_in, const int* in_sizes, int n_in,
                              void* d_out, int out_size, void* d_ws, size_t ws_size,
                              hipStream_t stream) {
    const float* xyz1    = (const float*)d_in[0];
    const float* xyz2    = (const float*)d_in[1];
    const float* points1 = (const float*)d_in[2];
    const float* points2 = (const float*)d_in[3];
    const float* w0      = (const float*)d_in[4];
    const float* b0      = (const float*)d_in[5];
    const float* gamma0  = (const float*)d_in[6];
    const float* beta0   = (const float*)d_in[7];
    const float* w1      = (const float*)d_in[8];
    const float* b1      = (const float*)d_in[9];
    const float* gamma1  = (const float*)d_in[10];
    const float* beta1   = (const float*)d_in[11];
    float* out = (float*)d_out;

    char* ws = (char*)d_ws;
    const size_t OFF_X    = 0;                       // 65536*512*2 = 67108864
    const size_t OFF_Y0   = 67108864;                // 65536*256*2 = 33554432
    const size_t OFF_Y1   = 100663296;               // 65536*128*2 = 16777216
    const size_t OFF_P2T  = 117440512;               // 16*1024*128*2 = 4194304
    const size_t OFF_W0B  = 121634816;               // 256*512*2 = 262144
    const size_t OFF_W1B  = 121896960;               // 128*256*2 = 65536
    const size_t OFF_STAT = 121962496;               // 1536 floats = 6144
    const size_t OFF_SDAT = 121968640;               // 16*1024*16 = 262144

    ushort_t* X    = (ushort_t*)(ws + OFF_X);
    ushort_t* Y0   = (ushort_t*)(ws + OFF_Y0);
    ushort_t* Y1   = (ushort_t*)(ws + OFF_Y1);
    ushort_t* p2t  = (ushort_t*)(ws + OFF_P2T);
    ushort_t* w0b  = (ushort_t*)(ws + OFF_W0B);
    ushort_t* w1b  = (ushort_t*)(ws + OFF_W1B);
    float* stats   = (float*)(ws + OFF_STAT);
    float4* sdat   = (float4*)(ws + OFF_SDAT);
    float* sum0 = stats;        float* ssq0 = stats + 256;
    float* sum1 = stats + 512;  float* ssq1 = stats + 640;
    float* a0   = stats + 768;  float* bb0  = stats + 1024;
    float* a1   = stats + 1280; float* bb1  = stats + 1408;

    hipMemsetAsync(stats, 0, 1536 * sizeof(float), stream);

    k_cvt<<<512, 256, 0, stream>>>(w0, w0b, 131072);
    k_cvt<<<128, 256, 0, stream>>>(w1, w1b, 32768);
    k_sdat<<<dim3(16, 4), 256, 0, stream>>>(xyz2, sdat);
    k_p2t<<<dim3(16, 4), 256, 0, stream>>>(points2, p2t);
    k_interp<<<dim3(16, 16), 256, 0, stream>>>(xyz1, sdat, points1, p2t, X);
    k_gemm<<<dim3(2, 512), 256, 0, stream>>>(w0b, X, b0, Y0, sum0, ssq0, 256, 512);
    k_bnfin<<<1, 256, 0, stream>>>(sum0, ssq0, gamma0, beta0, a0, bb0, 256, 1.0f / 65536.0f);
    k_act<<<8192, 256, 0, stream>>>(Y0, a0, bb0, 2097152);
    k_gemm<<<dim3(1, 512), 256, 0, stream>>>(w1b, Y0, b1, Y1, sum1, ssq1, 128, 256);
    k_bnfin<<<1, 128, 0, stream>>>(sum1, ssq1, gamma1, beta1, a1, bb1, 128, 1.0f / 65536.0f);
    k_out<<<dim3(16, 16), 256, 0, stream>>>(Y1, a1, bb1, out);
}

// Round 7
// 494.904 us; speedup vs baseline: 1.2387x; 1.2387x over previous
//
#include <hip/hip_runtime.h>
#include <stdint.h>

typedef unsigned short ushort_t;
typedef __attribute__((ext_vector_type(8))) __bf16 bf16x8;
typedef __attribute__((ext_vector_type(4))) float f32x4;

__device__ __forceinline__ float b2f(ushort_t u) {
    unsigned v = ((unsigned)u) << 16;
    float f;
    __builtin_memcpy(&f, &v, 4);
    return f;
}

__device__ __forceinline__ ushort_t f2b(float f) {
    unsigned u;
    __builtin_memcpy(&u, &f, 4);
    unsigned rounding = 0x7FFFu + ((u >> 16) & 1u);
    u += rounding;
    return (ushort_t)(u >> 16);
}

__device__ __forceinline__ void gl_lds16(const void* g, void* l) {
    __builtin_amdgcn_global_load_lds((const __attribute__((address_space(1))) void*)g,
                                     (__attribute__((address_space(3))) void*)l, 16, 0, 0);
}

// ---------------------------------------------------------------------------
__global__ __launch_bounds__(256) void k_cvt(const float* __restrict__ src,
                                             ushort_t* __restrict__ dst, int n) {
    int i = blockIdx.x * 256 + threadIdx.x;
    if (i < n) dst[i] = f2b(src[i]);
}

// ---------------------------------------------------------------------------
// sdat[b][s] = (x, y, z, |p|^2), strict fp32 norm order (matches reference)
__global__ __launch_bounds__(256) void k_sdat(const float* __restrict__ xyz2,
                                              float4* __restrict__ sdat) {
    int b = blockIdx.x;
    int s = blockIdx.y * 256 + threadIdx.x;
    const float* x2 = xyz2 + (size_t)b * 3 * 1024;
    float x = x2[s], y = x2[1024 + s], z = x2[2048 + s];
    float4 v;
    v.x = x; v.y = y; v.z = z;
    v.w = __fadd_rn(__fadd_rn(__fmul_rn(x, x), __fmul_rn(y, y)), __fmul_rn(z, z));
    sdat[(size_t)b * 1024 + s] = v;
}

// ---------------------------------------------------------------------------
// Transpose points2 [16][128][1024] (fp32) -> p2t [16][1024][128] (bf16)
// grid (16,16): 64 s-values/block, 4 channel-groups across threads
__global__ __launch_bounds__(256) void k_p2t(const float* __restrict__ points2,
                                             ushort_t* __restrict__ p2t) {
    int b = blockIdx.x;
    int t = threadIdx.x;
    int s = blockIdx.y * 64 + (t & 63);
    int g = t >> 6;
    const float* src = points2 + (size_t)b * 128 * 1024 + s;
    ushort_t* dst = p2t + ((size_t)b * 1024 + s) * 128;
#pragma unroll
    for (int i = 0; i < 4; ++i) {
        int cp = i * 4 + g;
        ushort_t tmp[8];
#pragma unroll
        for (int k = 0; k < 8; ++k) tmp[k] = f2b(src[(size_t)(cp * 8 + k) * 1024]);
        *(uint4*)(dst + cp * 8) = *(const uint4*)tmp;
    }
}

// ---------------------------------------------------------------------------
// 3-NN + build X [65536][512] bf16. 64 queries/block, 4 slice-threads/query.
// Distance expression BIT-IDENTICAL to the round-6 passing version:
//   dot = fma(z,pz, fma(y,py, x*px));  d = ((-2*dot) + |q|^2) + |p|^2
// Per-slice top-3 (ascending scan, strict <) then lexicographic (d,idx)
// 12-way merge == global ascending-scan semantics.
__global__ __launch_bounds__(256) void k_interp(const float* __restrict__ xyz1,
                                                const float4* __restrict__ sdat,
                                                const float* __restrict__ points1,
                                                const ushort_t* __restrict__ p2t,
                                                ushort_t* __restrict__ X) {
    int b = blockIdx.x;
    int n0 = blockIdx.y * 64;
    int t = threadIdx.x;
    int tq = t & 63;        // query within block
    int slice = t >> 6;     // 0..3, scans s in [slice*256, slice*256+256)

    __shared__ float sD[256 * 3];
    __shared__ int   sI[256 * 3];
    __shared__ int   sidx[64 * 3];
    __shared__ float sw[64 * 3];

    int n = n0 + tq;
    float x = xyz1[((size_t)b * 3 + 0) * 4096 + n];
    float y = xyz1[((size_t)b * 3 + 1) * 4096 + n];
    float z = xyz1[((size_t)b * 3 + 2) * 4096 + n];
    float s1 = __fadd_rn(__fadd_rn(__fmul_rn(x, x), __fmul_rn(y, y)), __fmul_rn(z, z));

    const float4* sd = sdat + (size_t)b * 1024;

    float d0 = 1e30f, d1 = 1e30f, d2 = 1e30f;
    int i0 = 0, i1 = 0, i2 = 0;
    int sbeg = slice * 256;
#pragma unroll 4
    for (int s = sbeg; s < sbeg + 256; ++s) {
        float4 v = sd[s];
        float dot = fmaf(z, v.z, fmaf(y, v.y, __fmul_rn(x, v.x)));
        float d = __fadd_rn(__fadd_rn(__fmul_rn(-2.0f, dot), s1), v.w);
        if (d < d2) {
            if (d < d1) {
                if (d < d0) { d2 = d1; i2 = i1; d1 = d0; i1 = i0; d0 = d; i0 = s; }
                else        { d2 = d1; i2 = i1; d1 = d;  i1 = s; }
            } else          { d2 = d;  i2 = s; }
        }
    }
    sD[t * 3 + 0] = d0; sD[t * 3 + 1] = d1; sD[t * 3 + 2] = d2;
    sI[t * 3 + 0] = i0; sI[t * 3 + 1] = i1; sI[t * 3 + 2] = i2;

    // points1 part: X[j][0:128] = bf16(points1[b][:, n]) — lanes span n
    {
        const float* p1base = points1 + (size_t)b * 128 * 4096 + n0 + (t & 63);
        ushort_t* dstbase = X + (size_t)(b * 4096 + n0 + (t & 63)) * 512;
#pragma unroll
        for (int i = 0; i < 4; ++i) {
            int piece = i * 4 + slice;
            ushort_t tmp[8];
#pragma unroll
            for (int k = 0; k < 8; ++k) tmp[k] = f2b(p1base[(size_t)(piece * 8 + k) * 4096]);
            *(uint4*)(dstbase + piece * 8) = *(const uint4*)tmp;
        }
    }
    __syncthreads();

    // merge: leader threads (t<64) pick global top-3 by lexicographic (d, idx)
    if (t < 64) {
        float cd[12]; int ci[12]; bool used[12];
#pragma unroll
        for (int sl = 0; sl < 4; ++sl) {
            int base = (sl * 64 + t) * 3;
#pragma unroll
            for (int r = 0; r < 3; ++r) {
                cd[sl * 3 + r] = sD[base + r];
                ci[sl * 3 + r] = sI[base + r];
                used[sl * 3 + r] = false;
            }
        }
        float seld[3]; int seli[3];
#pragma unroll
        for (int r = 0; r < 3; ++r) {
            float bd = 1e38f; int bi = 1 << 30; int bk = 0;
#pragma unroll
            for (int k = 0; k < 12; ++k) {
                if (used[k]) continue;
                bool better = (cd[k] < bd) || (cd[k] == bd && ci[k] < bi);
                if (better) { bd = cd[k]; bi = ci[k]; bk = k; }
            }
            seld[r] = bd; seli[r] = bi; used[bk] = true;
        }
        float r0 = 1.0f / (seld[0] + 1e-8f);
        float r1 = 1.0f / (seld[1] + 1e-8f);
        float r2 = 1.0f / (seld[2] + 1e-8f);
        float rs = r0 + r1 + r2;
        sw[t * 3 + 0] = r0 / rs; sw[t * 3 + 1] = r1 / rs; sw[t * 3 + 2] = r2 / rs;
        sidx[t * 3 + 0] = seli[0]; sidx[t * 3 + 1] = seli[1]; sidx[t * 3 + 2] = seli[2];
    }
    __syncthreads();

    // gather: X[j][128 + r*128 + d] = bf16(w_r * p2t[b][idx_r][d])
    // 64 queries x 48 pieces = 3072 items, 12 per thread
    int nl = t & 63;
#pragma unroll
    for (int i = 0; i < 12; ++i) {
        int rem = i * 4 + slice;       // 0..47
        int r = rem >> 4;
        int piece = rem & 15;
        int si = sidx[nl * 3 + r];
        float wt = sw[nl * 3 + r];
        const ushort_t* src = p2t + ((size_t)b * 1024 + si) * 128 + piece * 8;
        uint4 raw = *(const uint4*)src;
        ushort_t* e = (ushort_t*)&raw;
        ushort_t outv[8];
#pragma unroll
        for (int k = 0; k < 8; ++k) outv[k] = f2b(wt * b2f(e[k]));
        ushort_t* dst = X + (size_t)(b * 4096 + n0 + nl) * 512 + 128 + r * 128 + piece * 8;
        *(uint4*)dst = *(const uint4*)outv;
    }
}

// ---------------------------------------------------------------------------
// GEMM: Y[j][o] = sum_k A[o][k]*Bt[j][k] + bias[o]; per-o sum/sumsq atomics
__global__ __launch_bounds__(256) void k_gemm(const ushort_t* __restrict__ A,
                                              const ushort_t* __restrict__ Bt,
                                              const float* __restrict__ bias,
                                              ushort_t* __restrict__ Y,
                                              float* __restrict__ sum,
                                              float* __restrict__ ssq,
                                              int Mtot, int K) {
    __shared__ __align__(16) ushort_t As[128 * 32];
    __shared__ __align__(16) ushort_t Bs[128 * 32];

    int t = threadIdx.x;
    int m0 = blockIdx.x * 128;
    int j0 = blockIdx.y * 128;
    int wave = t >> 6, lane = t & 63;
    int wm = wave >> 1, wn = wave & 1;
    int l16 = lane & 15, quad = lane >> 4;

    f32x4 acc[4][4] = {};

    int nk = K >> 5;
    for (int kt = 0; kt < nk; ++kt) {
#pragma unroll
        for (int c = 0; c < 2; ++c) {
            int idx = c * 256 + t;
            int row = idx >> 2, kc = idx & 3;
            const ushort_t* srcA = A + (size_t)(m0 + row) * K + kt * 32 + kc * 8;
            const ushort_t* srcB = Bt + (size_t)(j0 + row) * K + kt * 32 + kc * 8;
            gl_lds16(srcA, As + idx * 8);
            gl_lds16(srcB, Bs + idx * 8);
        }
        __syncthreads();

        bf16x8 af[4], bfr[4];
#pragma unroll
        for (int mi = 0; mi < 4; ++mi)
            af[mi] = *(const bf16x8*)(As + (wm * 64 + mi * 16 + l16) * 32 + quad * 8);
#pragma unroll
        for (int ni = 0; ni < 4; ++ni)
            bfr[ni] = *(const bf16x8*)(Bs + (wn * 64 + ni * 16 + l16) * 32 + quad * 8);
#pragma unroll
        for (int mi = 0; mi < 4; ++mi)
#pragma unroll
            for (int ni = 0; ni < 4; ++ni)
                acc[mi][ni] = __builtin_amdgcn_mfma_f32_16x16x32_bf16(af[mi], bfr[ni], acc[mi][ni], 0, 0, 0);
        __syncthreads();
    }

#pragma unroll
    for (int mi = 0; mi < 4; ++mi) {
#pragma unroll
        for (int r = 0; r < 4; ++r) {
            int o = m0 + wm * 64 + mi * 16 + quad * 4 + r;
            float bv = bias[o];
            float s = 0.f, q = 0.f;
#pragma unroll
            for (int ni = 0; ni < 4; ++ni) {
                float v = acc[mi][ni][r] + bv;
                int j = j0 + wn * 64 + ni * 16 + l16;
                Y[(size_t)j * Mtot + o] = f2b(v);
                s += v;
                q += v * v;
            }
            s += __shfl_xor(s, 1); s += __shfl_xor(s, 2);
            s += __shfl_xor(s, 4); s += __shfl_xor(s, 8);
            q += __shfl_xor(q, 1); q += __shfl_xor(q, 2);
            q += __shfl_xor(q, 4); q += __shfl_xor(q, 8);
            if (l16 == 0) {
                atomicAdd(&sum[o], s);
                atomicAdd(&ssq[o], q);
            }
        }
    }
}

// ---------------------------------------------------------------------------
__global__ void k_bnfin(const float* __restrict__ sum, const float* __restrict__ ssq,
                        const float* __restrict__ gamma, const float* __restrict__ beta,
                        float* __restrict__ a, float* __restrict__ bb, int C, float inv_count) {
    int i = blockIdx.x * blockDim.x + threadIdx.x;
    if (i < C) {
        float mean = sum[i] * inv_count;
        float var = ssq[i] * inv_count - mean * mean;
        float sc = gamma[i] / sqrtf(var + 1e-5f);
        a[i] = sc;
        bb[i] = beta[i] - mean * sc;
    }
}

// ---------------------------------------------------------------------------
// In-place BN+ReLU on Y [cols][C] bf16 (C=256)
__global__ __launch_bounds__(256) void k_act(ushort_t* __restrict__ Y,
                                             const float* __restrict__ a,
                                             const float* __restrict__ bb,
                                             int total8) {
    __shared__ float sa[256], sb[256];
    for (int i = threadIdx.x; i < 256; i += 256) { sa[i] = a[i]; sb[i] = bb[i]; }
    __syncthreads();
    int idx = blockIdx.x * 256 + threadIdx.x;
    if (idx < total8) {
        ushort_t* p = Y + (size_t)idx * 8;
        int c0 = (idx * 8) & 255;
        uint4 raw = *(const uint4*)p;
        ushort_t* e = (ushort_t*)&raw;
#pragma unroll
        for (int k = 0; k < 8; ++k) {
            float v = b2f(e[k]);
            v = fmaxf(sa[c0 + k] * v + sb[c0 + k], 0.f);
            e[k] = f2b(v);
        }
        *(uint4*)p = raw;
    }
}

// ---------------------------------------------------------------------------
// Final BN+ReLU + transpose: Y1 [65536][128] bf16 -> out [16][128][4096] fp32
// grid (16,32): 128 n/block, channel dim split across 2 thread halves
__global__ __launch_bounds__(256) void k_out(const ushort_t* __restrict__ Y1,
                                             const float* __restrict__ a,
                                             const float* __restrict__ bb,
                                             float* __restrict__ out) {
    __shared__ float sa[128], sb[128];
    int t = threadIdx.x;
    if (t < 128) { sa[t] = a[t]; sb[t] = bb[t]; }
    __syncthreads();
    int b = blockIdx.x;
    int nl = t & 127;
    int half = t >> 7;
    int n = blockIdx.y * 128 + nl;
    const uint4* src = (const uint4*)(Y1 + (size_t)(b * 4096 + n) * 128);
    float* dst = out + (size_t)b * 128 * 4096 + n;
    uint4 raw[8];
#pragma unroll
    for (int p = 0; p < 8; ++p) raw[p] = src[half * 8 + p];
    const ushort_t* e = (const ushort_t*)raw;
#pragma unroll
    for (int c = 0; c < 64; ++c) {
        int ch = half * 64 + c;
        float v = b2f(e[c]);
        v = fmaxf(sa[ch] * v + sb[ch], 0.f);
        dst[(size_t)ch * 4096] = v;
    }
}

// ---------------------------------------------------------------------------
extern "C" void kernel_launch(void* const* d_in, const int* in_sizes, int n_in,
                              void* d_out, int out_size, void* d_ws, size_t ws_size,
                              hipStream_t stream) {
    const float* xyz1    = (const float*)d_in[0];
    const float* xyz2    = (const float*)d_in[1];
    const float* points1 = (const float*)d_in[2];
    const float* points2 = (const float*)d_in[3];
    const float* w0      = (const float*)d_in[4];
    const float* b0      = (const float*)d_in[5];
    const float* gamma0  = (const float*)d_in[6];
    const float* beta0   = (const float*)d_in[7];
    const float* w1      = (const float*)d_in[8];
    const float* b1      = (const float*)d_in[9];
    const float* gamma1  = (const float*)d_in[10];
    const float* beta1   = (const float*)d_in[11];
    float* out = (float*)d_out;

    char* ws = (char*)d_ws;
    const size_t OFF_X    = 0;                       // 65536*512*2 = 67108864
    const size_t OFF_Y0   = 67108864;                // 65536*256*2 = 33554432
    const size_t OFF_Y1   = 100663296;               // 65536*128*2 = 16777216
    const size_t OFF_P2T  = 117440512;               // 16*1024*128*2 = 4194304
    const size_t OFF_W0B  = 121634816;               // 256*512*2 = 262144
    const size_t OFF_W1B  = 121896960;               // 128*256*2 = 65536
    const size_t OFF_STAT = 121962496;               // 1536 floats = 6144
    const size_t OFF_SDAT = 121968640;               // 16*1024*16 = 262144

    ushort_t* X    = (ushort_t*)(ws + OFF_X);
    ushort_t* Y0   = (ushort_t*)(ws + OFF_Y0);
    ushort_t* Y1   = (ushort_t*)(ws + OFF_Y1);
    ushort_t* p2t  = (ushort_t*)(ws + OFF_P2T);
    ushort_t* w0b  = (ushort_t*)(ws + OFF_W0B);
    ushort_t* w1b  = (ushort_t*)(ws + OFF_W1B);
    float* stats   = (float*)(ws + OFF_STAT);
    float4* sdat   = (float4*)(ws + OFF_SDAT);
    float* sum0 = stats;        float* ssq0 = stats + 256;
    float* sum1 = stats + 512;  float* ssq1 = stats + 640;
    float* a0   = stats + 768;  float* bb0  = stats + 1024;
    float* a1   = stats + 1280; float* bb1  = stats + 1408;

    hipMemsetAsync(stats, 0, 1536 * sizeof(float), stream);

    k_cvt<<<512, 256, 0, stream>>>(w0, w0b, 131072);
    k_cvt<<<128, 256, 0, stream>>>(w1, w1b, 32768);
    k_sdat<<<dim3(16, 4), 256, 0, stream>>>(xyz2, sdat);
    k_p2t<<<dim3(16, 16), 256, 0, stream>>>(points2, p2t);
    k_interp<<<dim3(16, 64), 256, 0, stream>>>(xyz1, sdat, points1, p2t, X);
    k_gemm<<<dim3(2, 512), 256, 0, stream>>>(w0b, X, b0, Y0, sum0, ssq0, 256, 512);
    k_bnfin<<<1, 256, 0, stream>>>(sum0, ssq0, gamma0, beta0, a0, bb0, 256, 1.0f / 65536.0f);
    k_act<<<8192, 256, 0, stream>>>(Y0, a0, bb0, 2097152);
    k_gemm<<<dim3(1, 512), 256, 0, stream>>>(w1b, Y0, b1, Y1, sum1, ssq1, 128, 256);
    k_bnfin<<<1, 128, 0, stream>>>(sum1, ssq1, gamma1, beta1, a1, bb1, 128, 1.0f / 65536.0f);
    k_out<<<dim3(16, 32), 256, 0, stream>>>(Y1, a1, bb1, out);
}

// Round 8
// 324.927 us; speedup vs baseline: 1.8867x; 1.5231x over previous
//
#include <hip/hip_runtime.h>
#include <stdint.h>

typedef unsigned short ushort_t;
typedef __attribute__((ext_vector_type(8))) __bf16 bf16x8;
typedef __attribute__((ext_vector_type(4))) float f32x4;

__device__ __forceinline__ float b2f(ushort_t u) {
    unsigned v = ((unsigned)u) << 16;
    float f;
    __builtin_memcpy(&f, &v, 4);
    return f;
}

__device__ __forceinline__ ushort_t f2b(float f) {
    unsigned u;
    __builtin_memcpy(&u, &f, 4);
    unsigned rounding = 0x7FFFu + ((u >> 16) & 1u);
    u += rounding;
    return (ushort_t)(u >> 16);
}

__device__ __forceinline__ void gl_lds16(const void* g, void* l) {
    __builtin_amdgcn_global_load_lds((const __attribute__((address_space(1))) void*)g,
                                     (__attribute__((address_space(3))) void*)l, 16, 0, 0);
}

// ---------------------------------------------------------------------------
__global__ __launch_bounds__(256) void k_cvt(const float* __restrict__ src,
                                             ushort_t* __restrict__ dst, int n) {
    int i = blockIdx.x * 256 + threadIdx.x;
    if (i < n) dst[i] = f2b(src[i]);
}

// ---------------------------------------------------------------------------
// sdat[b][s] = (x, y, z, |p|^2), strict fp32 norm order (matches reference)
__global__ __launch_bounds__(256) void k_sdat(const float* __restrict__ xyz2,
                                              float4* __restrict__ sdat) {
    int b = blockIdx.x;
    int s = blockIdx.y * 256 + threadIdx.x;
    const float* x2 = xyz2 + (size_t)b * 3 * 1024;
    float x = x2[s], y = x2[1024 + s], z = x2[2048 + s];
    float4 v;
    v.x = x; v.y = y; v.z = z;
    v.w = __fadd_rn(__fadd_rn(__fmul_rn(x, x), __fmul_rn(y, y)), __fmul_rn(z, z));
    sdat[(size_t)b * 1024 + s] = v;
}

// ---------------------------------------------------------------------------
// Transpose points2 [16][128][1024] (fp32) -> p2t [16][1024][128] (bf16)
__global__ __launch_bounds__(256) void k_p2t(const float* __restrict__ points2,
                                             ushort_t* __restrict__ p2t) {
    int b = blockIdx.x;
    int t = threadIdx.x;
    int s = blockIdx.y * 64 + (t & 63);
    int g = t >> 6;
    const float* src = points2 + (size_t)b * 128 * 1024 + s;
    ushort_t* dst = p2t + ((size_t)b * 1024 + s) * 128;
#pragma unroll
    for (int i = 0; i < 4; ++i) {
        int cp = i * 4 + g;
        ushort_t tmp[8];
#pragma unroll
        for (int k = 0; k < 8; ++k) tmp[k] = f2b(src[(size_t)(cp * 8 + k) * 1024]);
        *(uint4*)(dst + cp * 8) = *(const uint4*)tmp;
    }
}

// ---------------------------------------------------------------------------
// 3-NN + build X [65536][512] bf16. 64 queries/block, 4 slice-threads/query.
// Distance expression BIT-IDENTICAL to the round-6 passing version.
__global__ __launch_bounds__(256) void k_interp(const float* __restrict__ xyz1,
                                                const float4* __restrict__ sdat,
                                                const float* __restrict__ points1,
                                                const ushort_t* __restrict__ p2t,
                                                ushort_t* __restrict__ X) {
    int b = blockIdx.x;
    int n0 = blockIdx.y * 64;
    int t = threadIdx.x;
    int tq = t & 63;
    int slice = t >> 6;

    __shared__ float sD[256 * 3];
    __shared__ int   sI[256 * 3];
    __shared__ int   sidx[64 * 3];
    __shared__ float sw[64 * 3];

    int n = n0 + tq;
    float x = xyz1[((size_t)b * 3 + 0) * 4096 + n];
    float y = xyz1[((size_t)b * 3 + 1) * 4096 + n];
    float z = xyz1[((size_t)b * 3 + 2) * 4096 + n];
    float s1 = __fadd_rn(__fadd_rn(__fmul_rn(x, x), __fmul_rn(y, y)), __fmul_rn(z, z));

    const float4* sd = sdat + (size_t)b * 1024;

    float d0 = 1e30f, d1 = 1e30f, d2 = 1e30f;
    int i0 = 0, i1 = 0, i2 = 0;
    int sbeg = slice * 256;
#pragma unroll 4
    for (int s = sbeg; s < sbeg + 256; ++s) {
        float4 v = sd[s];
        float dot = fmaf(z, v.z, fmaf(y, v.y, __fmul_rn(x, v.x)));
        float d = __fadd_rn(__fadd_rn(__fmul_rn(-2.0f, dot), s1), v.w);
        if (d < d2) {
            if (d < d1) {
                if (d < d0) { d2 = d1; i2 = i1; d1 = d0; i1 = i0; d0 = d; i0 = s; }
                else        { d2 = d1; i2 = i1; d1 = d;  i1 = s; }
            } else          { d2 = d;  i2 = s; }
        }
    }
    sD[t * 3 + 0] = d0; sD[t * 3 + 1] = d1; sD[t * 3 + 2] = d2;
    sI[t * 3 + 0] = i0; sI[t * 3 + 1] = i1; sI[t * 3 + 2] = i2;

    // points1 part: X[j][0:128] = bf16(points1[b][:, n])
    {
        const float* p1base = points1 + (size_t)b * 128 * 4096 + n0 + (t & 63);
        ushort_t* dstbase = X + (size_t)(b * 4096 + n0 + (t & 63)) * 512;
#pragma unroll
        for (int i = 0; i < 4; ++i) {
            int piece = i * 4 + slice;
            ushort_t tmp[8];
#pragma unroll
            for (int k = 0; k < 8; ++k) tmp[k] = f2b(p1base[(size_t)(piece * 8 + k) * 4096]);
            *(uint4*)(dstbase + piece * 8) = *(const uint4*)tmp;
        }
    }
    __syncthreads();

    if (t < 64) {
        float cd[12]; int ci[12]; bool used[12];
#pragma unroll
        for (int sl = 0; sl < 4; ++sl) {
            int base = (sl * 64 + t) * 3;
#pragma unroll
            for (int r = 0; r < 3; ++r) {
                cd[sl * 3 + r] = sD[base + r];
                ci[sl * 3 + r] = sI[base + r];
                used[sl * 3 + r] = false;
            }
        }
        float seld[3]; int seli[3];
#pragma unroll
        for (int r = 0; r < 3; ++r) {
            float bd = 1e38f; int bi = 1 << 30; int bk = 0;
#pragma unroll
            for (int k = 0; k < 12; ++k) {
                if (used[k]) continue;
                bool better = (cd[k] < bd) || (cd[k] == bd && ci[k] < bi);
                if (better) { bd = cd[k]; bi = ci[k]; bk = k; }
            }
            seld[r] = bd; seli[r] = bi; used[bk] = true;
        }
        float r0 = 1.0f / (seld[0] + 1e-8f);
        float r1 = 1.0f / (seld[1] + 1e-8f);
        float r2 = 1.0f / (seld[2] + 1e-8f);
        float rs = r0 + r1 + r2;
        sw[t * 3 + 0] = r0 / rs; sw[t * 3 + 1] = r1 / rs; sw[t * 3 + 2] = r2 / rs;
        sidx[t * 3 + 0] = seli[0]; sidx[t * 3 + 1] = seli[1]; sidx[t * 3 + 2] = seli[2];
    }
    __syncthreads();

    int nl = t & 63;
#pragma unroll
    for (int i = 0; i < 12; ++i) {
        int rem = i * 4 + slice;
        int r = rem >> 4;
        int piece = rem & 15;
        int si = sidx[nl * 3 + r];
        float wt = sw[nl * 3 + r];
        const ushort_t* src = p2t + ((size_t)b * 1024 + si) * 128 + piece * 8;
        uint4 raw = *(const uint4*)src;
        ushort_t* e = (ushort_t*)&raw;
        ushort_t outv[8];
#pragma unroll
        for (int k = 0; k < 8; ++k) outv[k] = f2b(wt * b2f(e[k]));
        ushort_t* dst = X + (size_t)(b * 4096 + n0 + nl) * 512 + 128 + r * 128 + piece * 8;
        *(uint4*)dst = *(const uint4*)outv;
    }
}

// ---------------------------------------------------------------------------
// GEMM: Y[j][o] = sum_k A[o][k]*Bt[j][k] + bias[o]
// Epilogue: LDS-staged coalesced bf16 store + deterministic per-block stats
// partials part_s/part_q [gridDim.y][Mtot].
__global__ __launch_bounds__(256) void k_gemm(const ushort_t* __restrict__ A,
                                              const ushort_t* __restrict__ Bt,
                                              const float* __restrict__ bias,
                                              ushort_t* __restrict__ Y,
                                              float* __restrict__ part_s,
                                              float* __restrict__ part_q,
                                              int Mtot, int K) {
    // smem layout: [0,8K) As | [8K,16K) Bs  — both dead after last K barrier
    //              [0,34816) sY (epilogue reuse) | [34816,35840) red_s/red_q
    __shared__ __align__(16) char smem[35840];
    ushort_t* As = (ushort_t*)smem;
    ushort_t* Bs = (ushort_t*)(smem + 8192);
    ushort_t* sY = (ushort_t*)smem;          // 128 rows x 136 elems
    float* red_s = (float*)(smem + 34816);   // 128
    float* red_q = red_s + 128;              // 128

    int t = threadIdx.x;
    int m0 = blockIdx.x * 128;
    int j0 = blockIdx.y * 128;
    int wave = t >> 6, lane = t & 63;
    int wm = wave >> 1, wn = wave & 1;
    int l16 = lane & 15, quad = lane >> 4;

    if (t < 128) { red_s[t] = 0.f; red_q[t] = 0.f; }

    f32x4 acc[4][4] = {};

    int nk = K >> 5;
    for (int kt = 0; kt < nk; ++kt) {
#pragma unroll
        for (int c = 0; c < 2; ++c) {
            int idx = c * 256 + t;
            int row = idx >> 2, kc = idx & 3;
            const ushort_t* srcA = A + (size_t)(m0 + row) * K + kt * 32 + kc * 8;
            const ushort_t* srcB = Bt + (size_t)(j0 + row) * K + kt * 32 + kc * 8;
            gl_lds16(srcA, As + idx * 8);
            gl_lds16(srcB, Bs + idx * 8);
        }
        __syncthreads();

        bf16x8 af[4], bfr[4];
#pragma unroll
        for (int mi = 0; mi < 4; ++mi)
            af[mi] = *(const bf16x8*)(As + (wm * 64 + mi * 16 + l16) * 32 + quad * 8);
#pragma unroll
        for (int ni = 0; ni < 4; ++ni)
            bfr[ni] = *(const bf16x8*)(Bs + (wn * 64 + ni * 16 + l16) * 32 + quad * 8);
#pragma unroll
        for (int mi = 0; mi < 4; ++mi)
#pragma unroll
            for (int ni = 0; ni < 4; ++ni)
                acc[mi][ni] = __builtin_amdgcn_mfma_f32_16x16x32_bf16(af[mi], bfr[ni], acc[mi][ni], 0, 0, 0);
        __syncthreads();
    }
    // As/Bs dead; sY reuse is safe from here.

#pragma unroll
    for (int mi = 0; mi < 4; ++mi) {
        int obase = wm * 64 + mi * 16 + quad * 4;
        float bv[4];
#pragma unroll
        for (int r = 0; r < 4; ++r) bv[r] = bias[m0 + obase + r];
        float sr[4] = {0.f, 0.f, 0.f, 0.f}, qr[4] = {0.f, 0.f, 0.f, 0.f};
#pragma unroll
        for (int ni = 0; ni < 4; ++ni) {
            int j_local = wn * 64 + ni * 16 + l16;
            ushort4 pk;
            float v0 = acc[mi][ni][0] + bv[0];
            float v1 = acc[mi][ni][1] + bv[1];
            float v2 = acc[mi][ni][2] + bv[2];
            float v3 = acc[mi][ni][3] + bv[3];
            pk.x = f2b(v0); pk.y = f2b(v1); pk.z = f2b(v2); pk.w = f2b(v3);
            sr[0] += v0; qr[0] += v0 * v0;
            sr[1] += v1; qr[1] += v1 * v1;
            sr[2] += v2; qr[2] += v2 * v2;
            sr[3] += v3; qr[3] += v3 * v3;
            *(ushort4*)(sY + j_local * 136 + obase) = pk;
        }
#pragma unroll
        for (int r = 0; r < 4; ++r) {
            float s = sr[r], q = qr[r];
            s += __shfl_xor(s, 1); s += __shfl_xor(s, 2);
            s += __shfl_xor(s, 4); s += __shfl_xor(s, 8);
            q += __shfl_xor(q, 1); q += __shfl_xor(q, 2);
            q += __shfl_xor(q, 4); q += __shfl_xor(q, 8);
            if (l16 == 0) {
                atomicAdd(&red_s[obase + r], s);
                atomicAdd(&red_q[obase + r], q);
            }
        }
    }
    __syncthreads();

    // coalesced flush: 128 rows x 128 o (bf16) = 2048 uint4
#pragma unroll
    for (int rep = 0; rep < 8; ++rep) {
        int idx = rep * 256 + t;
        int jl = idx >> 4;
        int o8 = idx & 15;
        uint4 vv = *(const uint4*)(sY + jl * 136 + o8 * 8);
        *(uint4*)(Y + (size_t)(j0 + jl) * Mtot + m0 + o8 * 8) = vv;
    }
    if (t < 128) {
        part_s[(size_t)blockIdx.y * Mtot + m0 + t] = red_s[t];
        part_q[(size_t)blockIdx.y * Mtot + m0 + t] = red_q[t];
    }
}

// ---------------------------------------------------------------------------
// BN finalize from per-block partials (deterministic)
__global__ void k_bnfin(const float* __restrict__ part_s, const float* __restrict__ part_q,
                        int nby,
                        const float* __restrict__ gamma, const float* __restrict__ beta,
                        float* __restrict__ a, float* __restrict__ bb, int C, float inv_count) {
    int i = threadIdx.x;
    if (i < C) {
        float s = 0.f, q = 0.f;
#pragma unroll 8
        for (int by = 0; by < nby; ++by) {
            s += part_s[(size_t)by * C + i];
            q += part_q[(size_t)by * C + i];
        }
        float mean = s * inv_count;
        float var = q * inv_count - mean * mean;
        float sc = gamma[i] / sqrtf(var + 1e-5f);
        a[i] = sc;
        bb[i] = beta[i] - mean * sc;
    }
}

// ---------------------------------------------------------------------------
// In-place BN+ReLU on Y [cols][C] bf16 (C=256)
__global__ __launch_bounds__(256) void k_act(ushort_t* __restrict__ Y,
                                             const float* __restrict__ a,
                                             const float* __restrict__ bb,
                                             int total8) {
    __shared__ float sa[256], sb[256];
    for (int i = threadIdx.x; i < 256; i += 256) { sa[i] = a[i]; sb[i] = bb[i]; }
    __syncthreads();
    int idx = blockIdx.x * 256 + threadIdx.x;
    if (idx < total8) {
        ushort_t* p = Y + (size_t)idx * 8;
        int c0 = (idx * 8) & 255;
        uint4 raw = *(const uint4*)p;
        ushort_t* e = (ushort_t*)&raw;
#pragma unroll
        for (int k = 0; k < 8; ++k) {
            float v = b2f(e[k]);
            v = fmaxf(sa[c0 + k] * v + sb[c0 + k], 0.f);
            e[k] = f2b(v);
        }
        *(uint4*)p = raw;
    }
}

// ---------------------------------------------------------------------------
// Final BN+ReLU + transpose: Y1 [65536][128] bf16 -> out [16][128][4096] fp32
__global__ __launch_bounds__(256) void k_out(const ushort_t* __restrict__ Y1,
                                             const float* __restrict__ a,
                                             const float* __restrict__ bb,
                                             float* __restrict__ out) {
    __shared__ float sa[128], sb[128];
    int t = threadIdx.x;
    if (t < 128) { sa[t] = a[t]; sb[t] = bb[t]; }
    __syncthreads();
    int b = blockIdx.x;
    int nl = t & 127;
    int half = t >> 7;
    int n = blockIdx.y * 128 + nl;
    const uint4* src = (const uint4*)(Y1 + (size_t)(b * 4096 + n) * 128);
    float* dst = out + (size_t)b * 128 * 4096 + n;
    uint4 raw[8];
#pragma unroll
    for (int p = 0; p < 8; ++p) raw[p] = src[half * 8 + p];
    const ushort_t* e = (const ushort_t*)raw;
#pragma unroll
    for (int c = 0; c < 64; ++c) {
        int ch = half * 64 + c;
        float v = b2f(e[c]);
        v = fmaxf(sa[ch] * v + sb[ch], 0.f);
        dst[(size_t)ch * 4096] = v;
    }
}

// ---------------------------------------------------------------------------
extern "C" void kernel_launch(void* const* d_in, const int* in_sizes, int n_in,
                              void* d_out, int out_size, void* d_ws, size_t ws_size,
                              hipStream_t stream) {
    const float* xyz1    = (const float*)d_in[0];
    const float* xyz2    = (const float*)d_in[1];
    const float* points1 = (const float*)d_in[2];
    const float* points2 = (const float*)d_in[3];
    const float* w0      = (const float*)d_in[4];
    const float* b0      = (const float*)d_in[5];
    const float* gamma0  = (const float*)d_in[6];
    const float* beta0   = (const float*)d_in[7];
    const float* w1      = (const float*)d_in[8];
    const float* b1      = (const float*)d_in[9];
    const float* gamma1  = (const float*)d_in[10];
    const float* beta1   = (const float*)d_in[11];
    float* out = (float*)d_out;

    char* ws = (char*)d_ws;
    const size_t OFF_X    = 0;                       // 65536*512*2 = 67108864
    const size_t OFF_Y0   = 67108864;                // 65536*256*2 = 33554432
    const size_t OFF_Y1   = 100663296;               // 65536*128*2 = 16777216
    const size_t OFF_P2T  = 117440512;               // 16*1024*128*2 = 4194304
    const size_t OFF_W0B  = 121634816;               // 262144
    const size_t OFF_W1B  = 121896960;               // 65536
    const size_t OFF_AB   = 121962496;               // 768 floats (a0,bb0,a1,bb1)
    const size_t OFF_SDAT = 121965568;               // 262144
    const size_t OFF_PS0  = 122227712;               // 512*256*4 = 524288
    const size_t OFF_PQ0  = 122752000;               // 524288
    const size_t OFF_PS1  = 123276288;               // 512*128*4 = 262144
    const size_t OFF_PQ1  = 123538432;               // 262144

    ushort_t* X    = (ushort_t*)(ws + OFF_X);
    ushort_t* Y0   = (ushort_t*)(ws + OFF_Y0);
    ushort_t* Y1   = (ushort_t*)(ws + OFF_Y1);
    ushort_t* p2t  = (ushort_t*)(ws + OFF_P2T);
    ushort_t* w0b  = (ushort_t*)(ws + OFF_W0B);
    ushort_t* w1b  = (ushort_t*)(ws + OFF_W1B);
    float* ab      = (float*)(ws + OFF_AB);
    float4* sdat   = (float4*)(ws + OFF_SDAT);
    float* ps0 = (float*)(ws + OFF_PS0);
    float* pq0 = (float*)(ws + OFF_PQ0);
    float* ps1 = (float*)(ws + OFF_PS1);
    float* pq1 = (float*)(ws + OFF_PQ1);
    float* a0 = ab;       float* bb0 = ab + 256;
    float* a1 = ab + 512; float* bb1 = ab + 640;

    k_cvt<<<512, 256, 0, stream>>>(w0, w0b, 131072);
    k_cvt<<<128, 256, 0, stream>>>(w1, w1b, 32768);
    k_sdat<<<dim3(16, 4), 256, 0, stream>>>(xyz2, sdat);
    k_p2t<<<dim3(16, 16), 256, 0, stream>>>(points2, p2t);
    k_interp<<<dim3(16, 64), 256, 0, stream>>>(xyz1, sdat, points1, p2t, X);
    k_gemm<<<dim3(2, 512), 256, 0, stream>>>(w0b, X, b0, Y0, ps0, pq0, 256, 512);
    k_bnfin<<<1, 256, 0, stream>>>(ps0, pq0, 512, gamma0, beta0, a0, bb0, 256, 1.0f / 65536.0f);
    k_act<<<8192, 256, 0, stream>>>(Y0, a0, bb0, 2097152);
    k_gemm<<<dim3(1, 512), 256, 0, stream>>>(w1b, Y0, b1, Y1, ps1, pq1, 128, 256);
    k_bnfin<<<1, 128, 0, stream>>>(ps1, pq1, 512, gamma1, beta1, a1, bb1, 128, 1.0f / 65536.0f);
    k_out<<<dim3(16, 32), 256, 0, stream>>>(Y1, a1, bb1, out);
}

// Round 9
// 291.769 us; speedup vs baseline: 2.1011x; 1.1136x over previous
//
#include <hip/hip_runtime.h>
#include <stdint.h>

typedef unsigned short ushort_t;
typedef __attribute__((ext_vector_type(8))) __bf16 bf16x8;
typedef __attribute__((ext_vector_type(4))) float f32x4;

__device__ __forceinline__ float b2f(ushort_t u) {
    unsigned v = ((unsigned)u) << 16;
    float f;
    __builtin_memcpy(&f, &v, 4);
    return f;
}

__device__ __forceinline__ ushort_t f2b(float f) {
    unsigned u;
    __builtin_memcpy(&u, &f, 4);
    unsigned rounding = 0x7FFFu + ((u >> 16) & 1u);
    u += rounding;
    return (ushort_t)(u >> 16);
}

__device__ __forceinline__ void gl_lds16(const void* g, void* l) {
    __builtin_amdgcn_global_load_lds((const __attribute__((address_space(1))) void*)g,
                                     (__attribute__((address_space(3))) void*)l, 16, 0, 0);
}

// ---------------------------------------------------------------------------
// Fused preprocessing: w0/w1 bf16-cvt, sdat build, points2 transpose.
// blockIdx ranges: [0,512) w0 | [512,640) w1 | [640,704) sdat | [704,960) p2t
__global__ __launch_bounds__(256) void k_pre(const float* __restrict__ w0, ushort_t* __restrict__ w0b,
                                             const float* __restrict__ w1, ushort_t* __restrict__ w1b,
                                             const float* __restrict__ xyz2, float4* __restrict__ sdat,
                                             const float* __restrict__ points2, ushort_t* __restrict__ p2t) {
    int bid = blockIdx.x;
    int t = threadIdx.x;
    if (bid < 512) {
        int i = bid * 256 + t;
        w0b[i] = f2b(w0[i]);
    } else if (bid < 640) {
        int i = (bid - 512) * 256 + t;
        w1b[i] = f2b(w1[i]);
    } else if (bid < 704) {
        int bb = bid - 640;
        int b = bb & 15, by = bb >> 4;
        int s = by * 256 + t;
        const float* x2 = xyz2 + (size_t)b * 3 * 1024;
        float x = x2[s], y = x2[1024 + s], z = x2[2048 + s];
        float4 v;
        v.x = x; v.y = y; v.z = z;
        v.w = __fadd_rn(__fadd_rn(__fmul_rn(x, x), __fmul_rn(y, y)), __fmul_rn(z, z));
        sdat[(size_t)b * 1024 + s] = v;
    } else {
        int bb = bid - 704;
        int b = bb & 15, sy = bb >> 4;
        int s = sy * 64 + (t & 63);
        int g = t >> 6;
        const float* src = points2 + (size_t)b * 128 * 1024 + s;
        ushort_t* dst = p2t + ((size_t)b * 1024 + s) * 128;
#pragma unroll
        for (int i = 0; i < 4; ++i) {
            int cp = i * 4 + g;
            ushort_t tmp[8];
#pragma unroll
            for (int k = 0; k < 8; ++k) tmp[k] = f2b(src[(size_t)(cp * 8 + k) * 1024]);
            *(uint4*)(dst + cp * 8) = *(const uint4*)tmp;
        }
    }
}

// ---------------------------------------------------------------------------
// 3-NN + build X [65536][512] bf16. 32 queries/block, 8 slices x 128 points.
// Distance expression BIT-IDENTICAL to the passing round-6 version.
// Branchless top-3 insert == strict-< ascending scan (case-verified, incl. ties).
__global__ __launch_bounds__(256) void k_interp(const float* __restrict__ xyz1,
                                                const float4* __restrict__ sdat,
                                                const float* __restrict__ points1,
                                                const ushort_t* __restrict__ p2t,
                                                ushort_t* __restrict__ X) {
    int b = blockIdx.x;
    int n0 = blockIdx.y * 32;
    int t = threadIdx.x;
    int tq = t & 31;        // query within block
    int slice = t >> 5;     // 0..7, scans s in [slice*128, slice*128+128)

    __shared__ float sD[256 * 3];
    __shared__ int   sI[256 * 3];
    __shared__ int   sidx[32 * 3];
    __shared__ float sw[32 * 3];

    int n = n0 + tq;
    float x = xyz1[((size_t)b * 3 + 0) * 4096 + n];
    float y = xyz1[((size_t)b * 3 + 1) * 4096 + n];
    float z = xyz1[((size_t)b * 3 + 2) * 4096 + n];
    float s1 = __fadd_rn(__fadd_rn(__fmul_rn(x, x), __fmul_rn(y, y)), __fmul_rn(z, z));

    const float4* sd = sdat + (size_t)b * 1024 + slice * 128;

    float d0 = 1e30f, d1 = 1e30f, d2 = 1e30f;
    int i0 = 0, i1 = 0, i2 = 0;
    int sbeg = slice * 128;
#pragma unroll 4
    for (int s = 0; s < 128; ++s) {
        float4 v = sd[s];
        float dot = fmaf(z, v.z, fmaf(y, v.y, __fmul_rn(x, v.x)));
        float d = __fadd_rn(__fadd_rn(__fmul_rn(-2.0f, dot), s1), v.w);
        int si = sbeg + s;
        bool c0 = d < d0, c1 = d < d1, c2 = d < d2;
        d2 = c1 ? d1 : (c2 ? d : d2);  i2 = c1 ? i1 : (c2 ? si : i2);
        d1 = c0 ? d0 : (c1 ? d : d1);  i1 = c0 ? i0 : (c1 ? si : i1);
        d0 = c0 ? d : d0;              i0 = c0 ? si : i0;
    }
    sD[t * 3 + 0] = d0; sD[t * 3 + 1] = d1; sD[t * 3 + 2] = d2;
    sI[t * 3 + 0] = i0; sI[t * 3 + 1] = i1; sI[t * 3 + 2] = i2;

    // points1 part: X[j][0:128] = bf16(points1[b][:, n]); lanes span 32 queries,
    // piece = i*8 + slice covers the 16 8-elem pieces over 2 iterations
    {
        const float* p1base = points1 + (size_t)b * 128 * 4096 + n0 + tq;
        ushort_t* dstbase = X + (size_t)(b * 4096 + n0 + tq) * 512;
#pragma unroll
        for (int i = 0; i < 2; ++i) {
            int piece = i * 8 + slice;
            ushort_t tmp[8];
#pragma unroll
            for (int k = 0; k < 8; ++k) tmp[k] = f2b(p1base[(size_t)(piece * 8 + k) * 4096]);
            *(uint4*)(dstbase + piece * 8) = *(const uint4*)tmp;
        }
    }
    __syncthreads();

    // merge: threads t<32 pick global top-3 over 24 candidates by lex (d, idx).
    // All candidate idx are distinct (disjoint slice ranges) -> exclude by idx.
    if (t < 32) {
        int sel0 = -1, sel1 = -1;
        float seld[3]; int seli[3];
#pragma unroll
        for (int r = 0; r < 3; ++r) {
            float bd = 1e38f; int bi = 1 << 30;
            for (int k = 0; k < 24; ++k) {
                int sl = k >> 2;          // wrong stride guard: k in 0..23 -> slice k/3
                // decode candidate k: slice = k/3, rank = k%3
                int slc = (k * 0x5556) >> 16;     // k/3 exact for k<=23
                int rank = k - slc * 3;
                int base = (slc * 32 + t) * 3 + rank;
                float cd = sD[base];
                int ci = sI[base];
                bool excl = (ci == sel0) | (ci == sel1);
                bool better = (!excl) & ((cd < bd) | ((cd == bd) & (ci < bi)));
                if (better) { bd = cd; bi = ci; }
                (void)sl;
            }
            seld[r] = bd; seli[r] = bi;
            if (r == 0) sel0 = bi; else if (r == 1) sel1 = bi;
        }
        float r0 = 1.0f / (seld[0] + 1e-8f);
        float r1 = 1.0f / (seld[1] + 1e-8f);
        float r2 = 1.0f / (seld[2] + 1e-8f);
        float rs = r0 + r1 + r2;
        sw[t * 3 + 0] = r0 / rs; sw[t * 3 + 1] = r1 / rs; sw[t * 3 + 2] = r2 / rs;
        sidx[t * 3 + 0] = seli[0]; sidx[t * 3 + 1] = seli[1]; sidx[t * 3 + 2] = seli[2];
    }
    __syncthreads();

    // gather: 32 queries x 48 pieces = 1536 items, idx -> (q, rem) so that
    // consecutive lanes touch contiguous bytes of one query row (stores ~16
    // lines/wave instead of 64).
#pragma unroll
    for (int i = 0; i < 6; ++i) {
        int idx = i * 256 + t;
        int q = (idx * 0x5556) >> 20;          // idx/48 via 1/48 ~ 0x5556/2^20 for idx<1536
        q = idx / 48;                          // let compiler emit exact magic-mul
        int rem = idx - q * 48;
        int r = rem >> 4;
        int piece = rem & 15;
        int si = sidx[q * 3 + r];
        float wt = sw[q * 3 + r];
        const ushort_t* src = p2t + ((size_t)b * 1024 + si) * 128 + piece * 8;
        uint4 raw = *(const uint4*)src;
        ushort_t* e = (ushort_t*)&raw;
        ushort_t outv[8];
#pragma unroll
        for (int k = 0; k < 8; ++k) outv[k] = f2b(wt * b2f(e[k]));
        ushort_t* dst = X + (size_t)(b * 4096 + n0 + q) * 512 + 128 + r * 128 + piece * 8;
        *(uint4*)dst = *(const uint4*)outv;
    }
}

// ---------------------------------------------------------------------------
// GEMM: Y[j][o] = sum_k A[o][k]*Bt[j][k] + bias[o]
// LDS-staged coalesced epilogue + deterministic per-block stats partials.
__global__ __launch_bounds__(256) void k_gemm(const ushort_t* __restrict__ A,
                                              const ushort_t* __restrict__ Bt,
                                              const float* __restrict__ bias,
                                              ushort_t* __restrict__ Y,
                                              float* __restrict__ part_s,
                                              float* __restrict__ part_q,
                                              int Mtot, int K) {
    __shared__ __align__(16) char smem[35840];
    ushort_t* As = (ushort_t*)smem;
    ushort_t* Bs = (ushort_t*)(smem + 8192);
    ushort_t* sY = (ushort_t*)smem;          // 128 rows x 136 elems
    float* red_s = (float*)(smem + 34816);   // 128
    float* red_q = red_s + 128;              // 128

    int t = threadIdx.x;
    int m0 = blockIdx.x * 128;
    int j0 = blockIdx.y * 128;
    int wave = t >> 6, lane = t & 63;
    int wm = wave >> 1, wn = wave & 1;
    int l16 = lane & 15, quad = lane >> 4;

    if (t < 128) { red_s[t] = 0.f; red_q[t] = 0.f; }

    f32x4 acc[4][4] = {};

    int nk = K >> 5;
    for (int kt = 0; kt < nk; ++kt) {
#pragma unroll
        for (int c = 0; c < 2; ++c) {
            int idx = c * 256 + t;
            int row = idx >> 2, kc = idx & 3;
            const ushort_t* srcA = A + (size_t)(m0 + row) * K + kt * 32 + kc * 8;
            const ushort_t* srcB = Bt + (size_t)(j0 + row) * K + kt * 32 + kc * 8;
            gl_lds16(srcA, As + idx * 8);
            gl_lds16(srcB, Bs + idx * 8);
        }
        __syncthreads();

        bf16x8 af[4], bfr[4];
#pragma unroll
        for (int mi = 0; mi < 4; ++mi)
            af[mi] = *(const bf16x8*)(As + (wm * 64 + mi * 16 + l16) * 32 + quad * 8);
#pragma unroll
        for (int ni = 0; ni < 4; ++ni)
            bfr[ni] = *(const bf16x8*)(Bs + (wn * 64 + ni * 16 + l16) * 32 + quad * 8);
#pragma unroll
        for (int mi = 0; mi < 4; ++mi)
#pragma unroll
            for (int ni = 0; ni < 4; ++ni)
                acc[mi][ni] = __builtin_amdgcn_mfma_f32_16x16x32_bf16(af[mi], bfr[ni], acc[mi][ni], 0, 0, 0);
        __syncthreads();
    }

#pragma unroll
    for (int mi = 0; mi < 4; ++mi) {
        int obase = wm * 64 + mi * 16 + quad * 4;
        float bv[4];
#pragma unroll
        for (int r = 0; r < 4; ++r) bv[r] = bias[m0 + obase + r];
        float sr[4] = {0.f, 0.f, 0.f, 0.f}, qr[4] = {0.f, 0.f, 0.f, 0.f};
#pragma unroll
        for (int ni = 0; ni < 4; ++ni) {
            int j_local = wn * 64 + ni * 16 + l16;
            ushort4 pk;
            float v0 = acc[mi][ni][0] + bv[0];
            float v1 = acc[mi][ni][1] + bv[1];
            float v2 = acc[mi][ni][2] + bv[2];
            float v3 = acc[mi][ni][3] + bv[3];
            pk.x = f2b(v0); pk.y = f2b(v1); pk.z = f2b(v2); pk.w = f2b(v3);
            sr[0] += v0; qr[0] += v0 * v0;
            sr[1] += v1; qr[1] += v1 * v1;
            sr[2] += v2; qr[2] += v2 * v2;
            sr[3] += v3; qr[3] += v3 * v3;
            *(ushort4*)(sY + j_local * 136 + obase) = pk;
        }
#pragma unroll
        for (int r = 0; r < 4; ++r) {
            float s = sr[r], q = qr[r];
            s += __shfl_xor(s, 1); s += __shfl_xor(s, 2);
            s += __shfl_xor(s, 4); s += __shfl_xor(s, 8);
            q += __shfl_xor(q, 1); q += __shfl_xor(q, 2);
            q += __shfl_xor(q, 4); q += __shfl_xor(q, 8);
            if (l16 == 0) {
                atomicAdd(&red_s[obase + r], s);
                atomicAdd(&red_q[obase + r], q);
            }
        }
    }
    __syncthreads();

#pragma unroll
    for (int rep = 0; rep < 8; ++rep) {
        int idx = rep * 256 + t;
        int jl = idx >> 4;
        int o8 = idx & 15;
        uint4 vv = *(const uint4*)(sY + jl * 136 + o8 * 8);
        *(uint4*)(Y + (size_t)(j0 + jl) * Mtot + m0 + o8 * 8) = vv;
    }
    if (t < 128) {
        part_s[(size_t)blockIdx.y * Mtot + m0 + t] = red_s[t];
        part_q[(size_t)blockIdx.y * Mtot + m0 + t] = red_q[t];
    }
}

// ---------------------------------------------------------------------------
__global__ void k_bnfin(const float* __restrict__ part_s, const float* __restrict__ part_q,
                        int nby,
                        const float* __restrict__ gamma, const float* __restrict__ beta,
                        float* __restrict__ a, float* __restrict__ bb, int C, float inv_count) {
    int i = threadIdx.x;
    if (i < C) {
        float s = 0.f, q = 0.f;
#pragma unroll 8
        for (int by = 0; by < nby; ++by) {
            s += part_s[(size_t)by * C + i];
            q += part_q[(size_t)by * C + i];
        }
        float mean = s * inv_count;
        float var = q * inv_count - mean * mean;
        float sc = gamma[i] / sqrtf(var + 1e-5f);
        a[i] = sc;
        bb[i] = beta[i] - mean * sc;
    }
}

// ---------------------------------------------------------------------------
__global__ __launch_bounds__(256) void k_act(ushort_t* __restrict__ Y,
                                             const float* __restrict__ a,
                                             const float* __restrict__ bb,
                                             int total8) {
    __shared__ float sa[256], sb[256];
    for (int i = threadIdx.x; i < 256; i += 256) { sa[i] = a[i]; sb[i] = bb[i]; }
    __syncthreads();
    int idx = blockIdx.x * 256 + threadIdx.x;
    if (idx < total8) {
        ushort_t* p = Y + (size_t)idx * 8;
        int c0 = (idx * 8) & 255;
        uint4 raw = *(const uint4*)p;
        ushort_t* e = (ushort_t*)&raw;
#pragma unroll
        for (int k = 0; k < 8; ++k) {
            float v = b2f(e[k]);
            v = fmaxf(sa[c0 + k] * v + sb[c0 + k], 0.f);
            e[k] = f2b(v);
        }
        *(uint4*)p = raw;
    }
}

// ---------------------------------------------------------------------------
__global__ __launch_bounds__(256) void k_out(const ushort_t* __restrict__ Y1,
                                             const float* __restrict__ a,
                                             const float* __restrict__ bb,
                                             float* __restrict__ out) {
    __shared__ float sa[128], sb[128];
    int t = threadIdx.x;
    if (t < 128) { sa[t] = a[t]; sb[t] = bb[t]; }
    __syncthreads();
    int b = blockIdx.x;
    int nl = t & 127;
    int half = t >> 7;
    int n = blockIdx.y * 128 + nl;
    const uint4* src = (const uint4*)(Y1 + (size_t)(b * 4096 + n) * 128);
    float* dst = out + (size_t)b * 128 * 4096 + n;
    uint4 raw[8];
#pragma unroll
    for (int p = 0; p < 8; ++p) raw[p] = src[half * 8 + p];
    const ushort_t* e = (const ushort_t*)raw;
#pragma unroll
    for (int c = 0; c < 64; ++c) {
        int ch = half * 64 + c;
        float v = b2f(e[c]);
        v = fmaxf(sa[ch] * v + sb[ch], 0.f);
        dst[(size_t)ch * 4096] = v;
    }
}

// ---------------------------------------------------------------------------
extern "C" void kernel_launch(void* const* d_in, const int* in_sizes, int n_in,
                              void* d_out, int out_size, void* d_ws, size_t ws_size,
                              hipStream_t stream) {
    const float* xyz1    = (const float*)d_in[0];
    const float* xyz2    = (const float*)d_in[1];
    const float* points1 = (const float*)d_in[2];
    const float* points2 = (const float*)d_in[3];
    const float* w0      = (const float*)d_in[4];
    const float* b0      = (const float*)d_in[5];
    const float* gamma0  = (const float*)d_in[6];
    const float* beta0   = (const float*)d_in[7];
    const float* w1      = (const float*)d_in[8];
    const float* b1      = (const float*)d_in[9];
    const float* gamma1  = (const float*)d_in[10];
    const float* beta1   = (const float*)d_in[11];
    float* out = (float*)d_out;

    char* ws = (char*)d_ws;
    const size_t OFF_X    = 0;                       // 67108864
    const size_t OFF_Y0   = 67108864;                // 33554432
    const size_t OFF_Y1   = 100663296;               // 16777216
    const size_t OFF_P2T  = 117440512;               // 4194304
    const size_t OFF_W0B  = 121634816;               // 262144
    const size_t OFF_W1B  = 121896960;               // 65536
    const size_t OFF_AB   = 121962496;               // 3072
    const size_t OFF_SDAT = 121965568;               // 262144
    const size_t OFF_PS0  = 122227712;               // 524288
    const size_t OFF_PQ0  = 122752000;               // 524288
    const size_t OFF_PS1  = 123276288;               // 262144
    const size_t OFF_PQ1  = 123538432;               // 262144

    ushort_t* X    = (ushort_t*)(ws + OFF_X);
    ushort_t* Y0   = (ushort_t*)(ws + OFF_Y0);
    ushort_t* Y1   = (ushort_t*)(ws + OFF_Y1);
    ushort_t* p2t  = (ushort_t*)(ws + OFF_P2T);
    ushort_t* w0b  = (ushort_t*)(ws + OFF_W0B);
    ushort_t* w1b  = (ushort_t*)(ws + OFF_W1B);
    float* ab      = (float*)(ws + OFF_AB);
    float4* sdat   = (float4*)(ws + OFF_SDAT);
    float* ps0 = (float*)(ws + OFF_PS0);
    float* pq0 = (float*)(ws + OFF_PQ0);
    float* ps1 = (float*)(ws + OFF_PS1);
    float* pq1 = (float*)(ws + OFF_PQ1);
    float* a0 = ab;       float* bb0 = ab + 256;
    float* a1 = ab + 512; float* bb1 = ab + 640;

    k_pre<<<960, 256, 0, stream>>>(w0, w0b, w1, w1b, xyz2, sdat, points2, p2t);
    k_interp<<<dim3(16, 128), 256, 0, stream>>>(xyz1, sdat, points1, p2t, X);
    k_gemm<<<dim3(2, 512), 256, 0, stream>>>(w0b, X, b0, Y0, ps0, pq0, 256, 512);
    k_bnfin<<<1, 256, 0, stream>>>(ps0, pq0, 512, gamma0, beta0, a0, bb0, 256, 1.0f / 65536.0f);
    k_act<<<8192, 256, 0, stream>>>(Y0, a0, bb0, 2097152);
    k_gemm<<<dim3(1, 512), 256, 0, stream>>>(w1b, Y0, b1, Y1, ps1, pq1, 128, 256);
    k_bnfin<<<1, 128, 0, stream>>>(ps1, pq1, 512, gamma1, beta1, a1, bb1, 128, 1.0f / 65536.0f);
    k_out<<<dim3(16, 32), 256, 0, stream>>>(Y1, a1, bb1, out);
}

// Round 10
// 263.214 us; speedup vs baseline: 2.3290x; 1.1085x over previous
//
#include <hip/hip_runtime.h>
#include <stdint.h>

typedef unsigned short ushort_t;
typedef __attribute__((ext_vector_type(8))) __bf16 bf16x8;
typedef __attribute__((ext_vector_type(4))) float f32x4;

__device__ __forceinline__ float b2f(ushort_t u) {
    unsigned v = ((unsigned)u) << 16;
    float f;
    __builtin_memcpy(&f, &v, 4);
    return f;
}

__device__ __forceinline__ ushort_t f2b(float f) {
    unsigned u;
    __builtin_memcpy(&u, &f, 4);
    unsigned rounding = 0x7FFFu + ((u >> 16) & 1u);
    u += rounding;
    return (ushort_t)(u >> 16);
}

__device__ __forceinline__ void gl_lds16(const void* g, void* l) {
    __builtin_amdgcn_global_load_lds((const __attribute__((address_space(1))) void*)g,
                                     (__attribute__((address_space(3))) void*)l, 16, 0, 0);
}

// ---------------------------------------------------------------------------
// Fused preprocessing: w0/w1 bf16-cvt, sdat build, points2 transpose.
__global__ __launch_bounds__(256) void k_pre(const float* __restrict__ w0, ushort_t* __restrict__ w0b,
                                             const float* __restrict__ w1, ushort_t* __restrict__ w1b,
                                             const float* __restrict__ xyz2, float4* __restrict__ sdat,
                                             const float* __restrict__ points2, ushort_t* __restrict__ p2t) {
    int bid = blockIdx.x;
    int t = threadIdx.x;
    if (bid < 512) {
        int i = bid * 256 + t;
        w0b[i] = f2b(w0[i]);
    } else if (bid < 640) {
        int i = (bid - 512) * 256 + t;
        w1b[i] = f2b(w1[i]);
    } else if (bid < 704) {
        int bb = bid - 640;
        int b = bb & 15, by = bb >> 4;
        int s = by * 256 + t;
        const float* x2 = xyz2 + (size_t)b * 3 * 1024;
        float x = x2[s], y = x2[1024 + s], z = x2[2048 + s];
        float4 v;
        v.x = x; v.y = y; v.z = z;
        v.w = __fadd_rn(__fadd_rn(__fmul_rn(x, x), __fmul_rn(y, y)), __fmul_rn(z, z));
        sdat[(size_t)b * 1024 + s] = v;
    } else {
        int bb = bid - 704;
        int b = bb & 15, sy = bb >> 4;
        int s = sy * 64 + (t & 63);
        int g = t >> 6;
        const float* src = points2 + (size_t)b * 128 * 1024 + s;
        ushort_t* dst = p2t + ((size_t)b * 1024 + s) * 128;
#pragma unroll
        for (int i = 0; i < 4; ++i) {
            int cp = i * 4 + g;
            ushort_t tmp[8];
#pragma unroll
            for (int k = 0; k < 8; ++k) tmp[k] = f2b(src[(size_t)(cp * 8 + k) * 1024]);
            *(uint4*)(dst + cp * 8) = *(const uint4*)tmp;
        }
    }
}

// ---------------------------------------------------------------------------
// 3-NN + build X [65536][512] bf16. 32 queries/block, 8 slices x 128 points.
// sdat[b] staged to LDS once per block; scan reads are half-wave broadcasts.
// Distance expression BIT-IDENTICAL to the passing round-6 version.
__global__ __launch_bounds__(256) void k_interp(const float* __restrict__ xyz1,
                                                const float4* __restrict__ sdat,
                                                const float* __restrict__ points1,
                                                const ushort_t* __restrict__ p2t,
                                                ushort_t* __restrict__ X) {
    int b = blockIdx.x;
    int n0 = blockIdx.y * 32;
    int t = threadIdx.x;
    int tq = t & 31;        // query within block
    int slice = t >> 5;     // 0..7
    int wave = t >> 6, lane = t & 63;

    __shared__ __align__(16) float4 sP[1024];   // 16 KB: staged sdat[b]
    __shared__ float sD[256 * 3];
    __shared__ int   sI[256 * 3];
    __shared__ int   sidx[32 * 3];
    __shared__ float sw[32 * 3];

    // stage sdat[b] -> LDS (wave w loads points [w*256, w*256+256))
    {
        const float4* src = sdat + (size_t)b * 1024;
#pragma unroll
        for (int c = 0; c < 4; ++c) {
            int p = wave * 256 + c * 64 + lane;
            gl_lds16(src + p, (char*)sP + p * 16);
        }
    }

    int n = n0 + tq;
    float x = xyz1[((size_t)b * 3 + 0) * 4096 + n];
    float y = xyz1[((size_t)b * 3 + 1) * 4096 + n];
    float z = xyz1[((size_t)b * 3 + 2) * 4096 + n];
    float s1 = __fadd_rn(__fadd_rn(__fmul_rn(x, x), __fmul_rn(y, y)), __fmul_rn(z, z));

    __syncthreads();   // staging complete

    float d0 = 1e30f, d1 = 1e30f, d2 = 1e30f;
    int i0 = 0, i1 = 0, i2 = 0;
    int sbeg = slice * 128;
    const float4* sdL = sP + sbeg;
#pragma unroll 8
    for (int s = 0; s < 128; ++s) {
        float4 v = sdL[s];
        float dot = fmaf(z, v.z, fmaf(y, v.y, __fmul_rn(x, v.x)));
        float d = __fadd_rn(__fadd_rn(__fmul_rn(-2.0f, dot), s1), v.w);
        int si = sbeg + s;
        bool c0 = d < d0, c1 = d < d1, c2 = d < d2;
        d2 = c1 ? d1 : (c2 ? d : d2);  i2 = c1 ? i1 : (c2 ? si : i2);
        d1 = c0 ? d0 : (c1 ? d : d1);  i1 = c0 ? i0 : (c1 ? si : i1);
        d0 = c0 ? d : d0;              i0 = c0 ? si : i0;
    }
    sD[t * 3 + 0] = d0; sD[t * 3 + 1] = d1; sD[t * 3 + 2] = d2;
    sI[t * 3 + 0] = i0; sI[t * 3 + 1] = i1; sI[t * 3 + 2] = i2;

    // points1 part: X[j][0:128] = bf16(points1[b][:, n])
    {
        const float* p1base = points1 + (size_t)b * 128 * 4096 + n0 + tq;
        ushort_t* dstbase = X + (size_t)(b * 4096 + n0 + tq) * 512;
#pragma unroll
        for (int i = 0; i < 2; ++i) {
            int piece = i * 8 + slice;
            ushort_t tmp[8];
#pragma unroll
            for (int k = 0; k < 8; ++k) tmp[k] = f2b(p1base[(size_t)(piece * 8 + k) * 4096]);
            *(uint4*)(dstbase + piece * 8) = *(const uint4*)tmp;
        }
    }
    __syncthreads();

    // merge: threads t<32 pick global top-3 of 24 candidates by lex (d, idx).
    if (t < 32) {
        int sel0 = -1, sel1 = -1;
        float seld[3]; int seli[3];
#pragma unroll
        for (int r = 0; r < 3; ++r) {
            float bd = 1e38f; int bi = 1 << 30;
            for (int k = 0; k < 24; ++k) {
                int slc = k >> 1;               // not used; decode below
                int s3 = (k * 0xAAAB) >> 17;    // k/3 for k<=23
                int rank = k - s3 * 3;
                int base = (s3 * 32 + t) * 3 + rank;
                float cd = sD[base];
                int ci = sI[base];
                bool excl = (ci == sel0) | (ci == sel1);
                bool better = (!excl) & ((cd < bd) | ((cd == bd) & (ci < bi)));
                if (better) { bd = cd; bi = ci; }
                (void)slc;
            }
            seld[r] = bd; seli[r] = bi;
            if (r == 0) sel0 = bi; else if (r == 1) sel1 = bi;
        }
        float r0 = 1.0f / (seld[0] + 1e-8f);
        float r1 = 1.0f / (seld[1] + 1e-8f);
        float r2 = 1.0f / (seld[2] + 1e-8f);
        float rs = r0 + r1 + r2;
        sw[t * 3 + 0] = r0 / rs; sw[t * 3 + 1] = r1 / rs; sw[t * 3 + 2] = r2 / rs;
        sidx[t * 3 + 0] = seli[0]; sidx[t * 3 + 1] = seli[1]; sidx[t * 3 + 2] = seli[2];
    }
    __syncthreads();

    // gather: 32 queries x 48 pieces = 1536 items
#pragma unroll
    for (int i = 0; i < 6; ++i) {
        int idx = i * 256 + t;
        int q = idx / 48;
        int rem = idx - q * 48;
        int r = rem >> 4;
        int piece = rem & 15;
        int si = sidx[q * 3 + r];
        float wt = sw[q * 3 + r];
        const ushort_t* src = p2t + ((size_t)b * 1024 + si) * 128 + piece * 8;
        uint4 raw = *(const uint4*)src;
        ushort_t* e = (ushort_t*)&raw;
        ushort_t outv[8];
#pragma unroll
        for (int k = 0; k < 8; ++k) outv[k] = f2b(wt * b2f(e[k]));
        ushort_t* dst = X + (size_t)(b * 4096 + n0 + q) * 512 + 128 + r * 128 + piece * 8;
        *(uint4*)dst = *(const uint4*)outv;
    }
}

// ---------------------------------------------------------------------------
// GEMM0: Y[j][o] = sum_k A[o][k]*Bt[j][k] + bias[o]
// LDS-staged coalesced epilogue + deterministic per-block stats partials.
__global__ __launch_bounds__(256) void k_gemm(const ushort_t* __restrict__ A,
                                              const ushort_t* __restrict__ Bt,
                                              const float* __restrict__ bias,
                                              ushort_t* __restrict__ Y,
                                              float* __restrict__ part_s,
                                              float* __restrict__ part_q,
                                              int Mtot, int K) {
    __shared__ __align__(16) char smem[35840];
    ushort_t* As = (ushort_t*)smem;
    ushort_t* Bs = (ushort_t*)(smem + 8192);
    ushort_t* sY = (ushort_t*)smem;          // 128 rows x 136 elems (epilogue)
    float* red_s = (float*)(smem + 34816);
    float* red_q = red_s + 128;

    int t = threadIdx.x;
    int m0 = blockIdx.x * 128;
    int j0 = blockIdx.y * 128;
    int wave = t >> 6, lane = t & 63;
    int wm = wave >> 1, wn = wave & 1;
    int l16 = lane & 15, quad = lane >> 4;

    if (t < 128) { red_s[t] = 0.f; red_q[t] = 0.f; }

    f32x4 acc[4][4] = {};

    int nk = K >> 5;
    for (int kt = 0; kt < nk; ++kt) {
#pragma unroll
        for (int c = 0; c < 2; ++c) {
            int idx = c * 256 + t;
            int row = idx >> 2, kc = idx & 3;
            gl_lds16(A + (size_t)(m0 + row) * K + kt * 32 + kc * 8, As + idx * 8);
            gl_lds16(Bt + (size_t)(j0 + row) * K + kt * 32 + kc * 8, Bs + idx * 8);
        }
        __syncthreads();

        bf16x8 af[4], bfr[4];
#pragma unroll
        for (int mi = 0; mi < 4; ++mi)
            af[mi] = *(const bf16x8*)(As + (wm * 64 + mi * 16 + l16) * 32 + quad * 8);
#pragma unroll
        for (int ni = 0; ni < 4; ++ni)
            bfr[ni] = *(const bf16x8*)(Bs + (wn * 64 + ni * 16 + l16) * 32 + quad * 8);
#pragma unroll
        for (int mi = 0; mi < 4; ++mi)
#pragma unroll
            for (int ni = 0; ni < 4; ++ni)
                acc[mi][ni] = __builtin_amdgcn_mfma_f32_16x16x32_bf16(af[mi], bfr[ni], acc[mi][ni], 0, 0, 0);
        __syncthreads();
    }

#pragma unroll
    for (int mi = 0; mi < 4; ++mi) {
        int obase = wm * 64 + mi * 16 + quad * 4;
        float bv[4];
#pragma unroll
        for (int r = 0; r < 4; ++r) bv[r] = bias[m0 + obase + r];
        float sr[4] = {0.f, 0.f, 0.f, 0.f}, qr[4] = {0.f, 0.f, 0.f, 0.f};
#pragma unroll
        for (int ni = 0; ni < 4; ++ni) {
            int j_local = wn * 64 + ni * 16 + l16;
            ushort4 pk;
            float v0 = acc[mi][ni][0] + bv[0];
            float v1 = acc[mi][ni][1] + bv[1];
            float v2 = acc[mi][ni][2] + bv[2];
            float v3 = acc[mi][ni][3] + bv[3];
            pk.x = f2b(v0); pk.y = f2b(v1); pk.z = f2b(v2); pk.w = f2b(v3);
            sr[0] += v0; qr[0] += v0 * v0;
            sr[1] += v1; qr[1] += v1 * v1;
            sr[2] += v2; qr[2] += v2 * v2;
            sr[3] += v3; qr[3] += v3 * v3;
            *(ushort4*)(sY + j_local * 136 + obase) = pk;
        }
#pragma unroll
        for (int r = 0; r < 4; ++r) {
            float s = sr[r], q = qr[r];
            s += __shfl_xor(s, 1); s += __shfl_xor(s, 2);
            s += __shfl_xor(s, 4); s += __shfl_xor(s, 8);
            q += __shfl_xor(q, 1); q += __shfl_xor(q, 2);
            q += __shfl_xor(q, 4); q += __shfl_xor(q, 8);
            if (l16 == 0) {
                atomicAdd(&red_s[obase + r], s);
                atomicAdd(&red_q[obase + r], q);
            }
        }
    }
    __syncthreads();

#pragma unroll
    for (int rep = 0; rep < 8; ++rep) {
        int idx = rep * 256 + t;
        int jl = idx >> 4;
        int o8 = idx & 15;
        uint4 vv = *(const uint4*)(sY + jl * 136 + o8 * 8);
        *(uint4*)(Y + (size_t)(j0 + jl) * Mtot + m0 + o8 * 8) = vv;
    }
    if (t < 128) {
        part_s[(size_t)blockIdx.y * Mtot + m0 + t] = red_s[t];
        part_q[(size_t)blockIdx.y * Mtot + m0 + t] = red_q[t];
    }
}

// ---------------------------------------------------------------------------
// GEMM1 with fused BN0+ReLU applied to the B (Y0) tiles at staging time.
// Math identical to the former k_act + k_gemm pair.
__global__ __launch_bounds__(256) void k_gemmf(const ushort_t* __restrict__ A,
                                               const ushort_t* __restrict__ Y0,
                                               const float* __restrict__ bias,
                                               const float* __restrict__ act_a,
                                               const float* __restrict__ act_b,
                                               ushort_t* __restrict__ Y,
                                               float* __restrict__ part_s,
                                               float* __restrict__ part_q,
                                               int Mtot, int K) {
    __shared__ __align__(16) char smem[35840];
    ushort_t* As = (ushort_t*)smem;
    ushort_t* Bs = (ushort_t*)(smem + 8192);
    float* sa = (float*)(smem + 16384);      // 256 floats (K<=256)
    float* sb = sa + 256;
    ushort_t* sY = (ushort_t*)smem;          // epilogue reuse
    float* red_s = (float*)(smem + 34816);
    float* red_q = red_s + 128;

    int t = threadIdx.x;
    int m0 = blockIdx.x * 128;
    int j0 = blockIdx.y * 128;
    int wave = t >> 6, lane = t & 63;
    int wm = wave >> 1, wn = wave & 1;
    int l16 = lane & 15, quad = lane >> 4;

    sa[t] = act_a[t]; sb[t] = act_b[t];
    if (t < 128) { red_s[t] = 0.f; red_q[t] = 0.f; }
    __syncthreads();

    f32x4 acc[4][4] = {};

    int nk = K >> 5;
    for (int kt = 0; kt < nk; ++kt) {
#pragma unroll
        for (int c = 0; c < 2; ++c) {
            int idx = c * 256 + t;
            int row = idx >> 2, kc = idx & 3;
            gl_lds16(A + (size_t)(m0 + row) * K + kt * 32 + kc * 8, As + idx * 8);
        }
#pragma unroll
        for (int c = 0; c < 2; ++c) {
            int idx = c * 256 + t;
            int row = idx >> 2, kc = idx & 3;
            int cbase = kt * 32 + kc * 8;
            uint4 raw = *(const uint4*)(Y0 + (size_t)(j0 + row) * K + cbase);
            ushort_t* e = (ushort_t*)&raw;
            ushort_t outv[8];
#pragma unroll
            for (int k = 0; k < 8; ++k) {
                float v = fmaxf(sa[cbase + k] * b2f(e[k]) + sb[cbase + k], 0.f);
                outv[k] = f2b(v);
            }
            *(uint4*)(Bs + idx * 8) = *(const uint4*)outv;
        }
        __syncthreads();

        bf16x8 af[4], bfr[4];
#pragma unroll
        for (int mi = 0; mi < 4; ++mi)
            af[mi] = *(const bf16x8*)(As + (wm * 64 + mi * 16 + l16) * 32 + quad * 8);
#pragma unroll
        for (int ni = 0; ni < 4; ++ni)
            bfr[ni] = *(const bf16x8*)(Bs + (wn * 64 + ni * 16 + l16) * 32 + quad * 8);
#pragma unroll
        for (int mi = 0; mi < 4; ++mi)
#pragma unroll
            for (int ni = 0; ni < 4; ++ni)
                acc[mi][ni] = __builtin_amdgcn_mfma_f32_16x16x32_bf16(af[mi], bfr[ni], acc[mi][ni], 0, 0, 0);
        __syncthreads();
    }

#pragma unroll
    for (int mi = 0; mi < 4; ++mi) {
        int obase = wm * 64 + mi * 16 + quad * 4;
        float bv[4];
#pragma unroll
        for (int r = 0; r < 4; ++r) bv[r] = bias[m0 + obase + r];
        float sr[4] = {0.f, 0.f, 0.f, 0.f}, qr[4] = {0.f, 0.f, 0.f, 0.f};
#pragma unroll
        for (int ni = 0; ni < 4; ++ni) {
            int j_local = wn * 64 + ni * 16 + l16;
            ushort4 pk;
            float v0 = acc[mi][ni][0] + bv[0];
            float v1 = acc[mi][ni][1] + bv[1];
            float v2 = acc[mi][ni][2] + bv[2];
            float v3 = acc[mi][ni][3] + bv[3];
            pk.x = f2b(v0); pk.y = f2b(v1); pk.z = f2b(v2); pk.w = f2b(v3);
            sr[0] += v0; qr[0] += v0 * v0;
            sr[1] += v1; qr[1] += v1 * v1;
            sr[2] += v2; qr[2] += v2 * v2;
            sr[3] += v3; qr[3] += v3 * v3;
            *(ushort4*)(sY + j_local * 136 + obase) = pk;
        }
#pragma unroll
        for (int r = 0; r < 4; ++r) {
            float s = sr[r], q = qr[r];
            s += __shfl_xor(s, 1); s += __shfl_xor(s, 2);
            s += __shfl_xor(s, 4); s += __shfl_xor(s, 8);
            q += __shfl_xor(q, 1); q += __shfl_xor(q, 2);
            q += __shfl_xor(q, 4); q += __shfl_xor(q, 8);
            if (l16 == 0) {
                atomicAdd(&red_s[obase + r], s);
                atomicAdd(&red_q[obase + r], q);
            }
        }
    }
    __syncthreads();

#pragma unroll
    for (int rep = 0; rep < 8; ++rep) {
        int idx = rep * 256 + t;
        int jl = idx >> 4;
        int o8 = idx & 15;
        uint4 vv = *(const uint4*)(sY + jl * 136 + o8 * 8);
        *(uint4*)(Y + (size_t)(j0 + jl) * Mtot + m0 + o8 * 8) = vv;
    }
    if (t < 128) {
        part_s[(size_t)blockIdx.y * Mtot + m0 + t] = red_s[t];
        part_q[(size_t)blockIdx.y * Mtot + m0 + t] = red_q[t];
    }
}

// ---------------------------------------------------------------------------
__global__ void k_bnfin(const float* __restrict__ part_s, const float* __restrict__ part_q,
                        int nby,
                        const float* __restrict__ gamma, const float* __restrict__ beta,
                        float* __restrict__ a, float* __restrict__ bb, int C, float inv_count) {
    int i = threadIdx.x;
    if (i < C) {
        float s = 0.f, q = 0.f;
#pragma unroll 8
        for (int by = 0; by < nby; ++by) {
            s += part_s[(size_t)by * C + i];
            q += part_q[(size_t)by * C + i];
        }
        float mean = s * inv_count;
        float var = q * inv_count - mean * mean;
        float sc = gamma[i] / sqrtf(var + 1e-5f);
        a[i] = sc;
        bb[i] = beta[i] - mean * sc;
    }
}

// ---------------------------------------------------------------------------
__global__ __launch_bounds__(256) void k_out(const ushort_t* __restrict__ Y1,
                                             const float* __restrict__ a,
                                             const float* __restrict__ bb,
                                             float* __restrict__ out) {
    __shared__ float sa[128], sb[128];
    int t = threadIdx.x;
    if (t < 128) { sa[t] = a[t]; sb[t] = bb[t]; }
    __syncthreads();
    int b = blockIdx.x;
    int nl = t & 127;
    int half = t >> 7;
    int n = blockIdx.y * 128 + nl;
    const uint4* src = (const uint4*)(Y1 + (size_t)(b * 4096 + n) * 128);
    float* dst = out + (size_t)b * 128 * 4096 + n;
    uint4 raw[8];
#pragma unroll
    for (int p = 0; p < 8; ++p) raw[p] = src[half * 8 + p];
    const ushort_t* e = (const ushort_t*)raw;
#pragma unroll
    for (int c = 0; c < 64; ++c) {
        int ch = half * 64 + c;
        float v = b2f(e[c]);
        v = fmaxf(sa[ch] * v + sb[ch], 0.f);
        dst[(size_t)ch * 4096] = v;
    }
}

// ---------------------------------------------------------------------------
extern "C" void kernel_launch(void* const* d_in, const int* in_sizes, int n_in,
                              void* d_out, int out_size, void* d_ws, size_t ws_size,
                              hipStream_t stream) {
    const float* xyz1    = (const float*)d_in[0];
    const float* xyz2    = (const float*)d_in[1];
    const float* points1 = (const float*)d_in[2];
    const float* points2 = (const float*)d_in[3];
    const float* w0      = (const float*)d_in[4];
    const float* b0      = (const float*)d_in[5];
    const float* gamma0  = (const float*)d_in[6];
    const float* beta0   = (const float*)d_in[7];
    const float* w1      = (const float*)d_in[8];
    const float* b1      = (const float*)d_in[9];
    const float* gamma1  = (const float*)d_in[10];
    const float* beta1   = (const float*)d_in[11];
    float* out = (float*)d_out;

    char* ws = (char*)d_ws;
    const size_t OFF_X    = 0;                       // 67108864
    const size_t OFF_Y0   = 67108864;                // 33554432
    const size_t OFF_Y1   = 100663296;               // 16777216
    const size_t OFF_P2T  = 117440512;               // 4194304
    const size_t OFF_W0B  = 121634816;               // 262144
    const size_t OFF_W1B  = 121896960;               // 65536
    const size_t OFF_AB   = 121962496;               // 3072
    const size_t OFF_SDAT = 121965568;               // 262144
    const size_t OFF_PS0  = 122227712;               // 524288
    const size_t OFF_PQ0  = 122752000;               // 524288
    const size_t OFF_PS1  = 123276288;               // 262144
    const size_t OFF_PQ1  = 123538432;               // 262144

    ushort_t* X    = (ushort_t*)(ws + OFF_X);
    ushort_t* Y0   = (ushort_t*)(ws + OFF_Y0);
    ushort_t* Y1   = (ushort_t*)(ws + OFF_Y1);
    ushort_t* p2t  = (ushort_t*)(ws + OFF_P2T);
    ushort_t* w0b  = (ushort_t*)(ws + OFF_W0B);
    ushort_t* w1b  = (ushort_t*)(ws + OFF_W1B);
    float* ab      = (float*)(ws + OFF_AB);
    float4* sdat   = (float4*)(ws + OFF_SDAT);
    float* ps0 = (float*)(ws + OFF_PS0);
    float* pq0 = (float*)(ws + OFF_PQ0);
    float* ps1 = (float*)(ws + OFF_PS1);
    float* pq1 = (float*)(ws + OFF_PQ1);
    float* a0 = ab;       float* bb0 = ab + 256;
    float* a1 = ab + 512; float* bb1 = ab + 640;

    k_pre<<<960, 256, 0, stream>>>(w0, w0b, w1, w1b, xyz2, sdat, points2, p2t);
    k_interp<<<dim3(16, 128), 256, 0, stream>>>(xyz1, sdat, points1, p2t, X);
    k_gemm<<<dim3(2, 512), 256, 0, stream>>>(w0b, X, b0, Y0, ps0, pq0, 256, 512);
    k_bnfin<<<1, 256, 0, stream>>>(ps0, pq0, 512, gamma0, beta0, a0, bb0, 256, 1.0f / 65536.0f);
    k_gemmf<<<dim3(1, 512), 256, 0, stream>>>(w1b, Y0, b1, a0, bb0, Y1, ps1, pq1, 128, 256);
    k_bnfin<<<1, 128, 0, stream>>>(ps1, pq1, 512, gamma1, beta1, a1, bb1, 128, 1.0f / 65536.0f);
    k_out<<<dim3(16, 32), 256, 0, stream>>>(Y1, a1, bb1, out);
}